// Round 1
// baseline (1664.706 us; speedup 1.0000x reference)
//
#include <hip/hip_runtime.h>

// GraphTransformerBlock2: GATConv(H=3,C=64, edge_dim=5, self-loops w/ mean fill)
// -> linear1 -> LN(x + .) -> linear2 -> LN(lin + .)
// All float32. edge_index int32, layout (2,E) row-major: src=ei[0:E], dst=ei[E:2E].

#define HH 3
#define CC 64
#define DIN 64
#define ED 5
#define HC (HH*CC)          // 192
#define NEG_SLOPE 0.2f
#define LN_EPS 1e-5f

// ---- ordered-uint encoding for float atomicMax ----
__device__ __forceinline__ unsigned enc_f32(float f) {
    unsigned u = __float_as_uint(f);
    return (u & 0x80000000u) ? ~u : (u | 0x80000000u);
}
__device__ __forceinline__ float dec_f32(unsigned u) {
    u = (u & 0x80000000u) ? (u & 0x7FFFFFFFu) : ~u;
    return __uint_as_float(u);
}

__device__ __forceinline__ float wave_sum(float v) {
    #pragma unroll
    for (int o = 32; o; o >>= 1) v += __shfl_xor(v, o, 64);
    return v;
}

// we[d][h] = sum_c lin_edge_w[d, h*64+c] * att_edge[h, c]   (5x3)
__global__ __launch_bounds__(64) void k_we(const float* __restrict__ lin_edge_w,
                                           const float* __restrict__ att_edge,
                                           float* __restrict__ we) {
    int t = threadIdx.x;
    if (t >= ED * HH) return;
    int d = t / HH, h = t % HH;
    float s = 0.f;
    for (int c = 0; c < CC; ++c)
        s += lin_edge_w[d * HC + h * CC + c] * att_edge[h * CC + c];
    we[d * HH + h] = s;
}

// per-dst sums of edge_attr + counts (for self-loop fill_value='mean')
__global__ __launch_bounds__(256) void k_edge_accum(const float* __restrict__ ea,
                                                    const int* __restrict__ ei,
                                                    float* __restrict__ attr_sum,
                                                    float* __restrict__ cnt, int E) {
    int e = blockIdx.x * blockDim.x + threadIdx.x;
    if (e >= E) return;
    int d = ei[E + e];
    #pragma unroll
    for (int j = 0; j < ED; ++j) atomicAdd(&attr_sum[d * ED + j], ea[e * ED + j]);
    atomicAdd(&cnt[d], 1.0f);
}

// xs = x @ lin_w  (N x 192), plus a_src[n,h], a_dst[n,h]
__global__ __launch_bounds__(256) void k_xs(const float* __restrict__ x,
                                            const float* __restrict__ lin_w,
                                            const float* __restrict__ att_src,
                                            const float* __restrict__ att_dst,
                                            float* __restrict__ xs,
                                            float* __restrict__ a_src,
                                            float* __restrict__ a_dst, int N) {
    __shared__ float wl[DIN * HC];                 // 64*192 f32 = 48 KB
    for (int i = threadIdx.x; i < DIN * HC; i += 256) wl[i] = lin_w[i];
    __syncthreads();
    int lane = threadIdx.x & 63;
    int wid  = threadIdx.x >> 6;
    float as0 = att_src[0 * CC + lane], as1 = att_src[1 * CC + lane], as2 = att_src[2 * CC + lane];
    float ad0 = att_dst[0 * CC + lane], ad1 = att_dst[1 * CC + lane], ad2 = att_dst[2 * CC + lane];
    for (int n = blockIdx.x * 4 + wid; n < N; n += gridDim.x * 4) {
        float xv = x[(size_t)n * DIN + lane];
        float a0 = 0.f, a1 = 0.f, a2 = 0.f;
        #pragma unroll
        for (int d = 0; d < DIN; ++d) {
            float xd = __shfl(xv, d, 64);
            a0 += xd * wl[d * HC + 0 * CC + lane];
            a1 += xd * wl[d * HC + 1 * CC + lane];
            a2 += xd * wl[d * HC + 2 * CC + lane];
        }
        size_t base = (size_t)n * HC;
        xs[base + 0 * CC + lane] = a0;
        xs[base + 1 * CC + lane] = a1;
        xs[base + 2 * CC + lane] = a2;
        float s0 = wave_sum(a0 * as0), s1 = wave_sum(a1 * as1), s2 = wave_sum(a2 * as2);
        float d0 = wave_sum(a0 * ad0), d1 = wave_sum(a1 * ad1), d2 = wave_sum(a2 * ad2);
        if (lane == 0) {
            a_src[n * HH + 0] = s0; a_src[n * HH + 1] = s1; a_src[n * HH + 2] = s2;
            a_dst[n * HH + 0] = d0; a_dst[n * HH + 1] = d1; a_dst[n * HH + 2] = d2;
        }
    }
}

// attr_sum -> loop_attr (divide by max(cnt,1)) in place
__global__ __launch_bounds__(256) void k_loop_attr(float* __restrict__ attr_sum,
                                                   const float* __restrict__ cnt, int N) {
    int n = blockIdx.x * blockDim.x + threadIdx.x;
    if (n >= N) return;
    float c = fmaxf(cnt[n], 1.0f);
    #pragma unroll
    for (int j = 0; j < ED; ++j) attr_sum[n * ED + j] /= c;
}

// logits (leaky-relu'd) + segment max via ordered-uint atomicMax
__global__ __launch_bounds__(256) void k_logits(const float* __restrict__ ea,
                                                const float* __restrict__ loop_attr,
                                                const int* __restrict__ ei,
                                                const float* __restrict__ a_src,
                                                const float* __restrict__ a_dst,
                                                const float* __restrict__ we,
                                                float* __restrict__ logits,
                                                unsigned* __restrict__ lmax, int E, int N) {
    int e = blockIdx.x * blockDim.x + threadIdx.x;
    int E2 = E + N;
    if (e >= E2) return;
    int s, d;
    float attr[ED];
    if (e < E) {
        s = ei[e]; d = ei[E + e];
        #pragma unroll
        for (int j = 0; j < ED; ++j) attr[j] = ea[(size_t)e * ED + j];
    } else {
        s = d = e - E;
        #pragma unroll
        for (int j = 0; j < ED; ++j) attr[j] = loop_attr[(size_t)s * ED + j];
    }
    #pragma unroll
    for (int h = 0; h < HH; ++h) {
        float aeg = 0.f;
        #pragma unroll
        for (int j = 0; j < ED; ++j) aeg += attr[j] * we[j * HH + h];
        float l = a_src[s * HH + h] + a_dst[d * HH + h] + aeg;
        l = (l >= 0.f) ? l : NEG_SLOPE * l;
        logits[(size_t)e * HH + h] = l;
        atomicMax(&lmax[d * HH + h], enc_f32(l));
    }
}

// ex = exp(logit - lmax[dst]); denom += ex (ex overwrites logits buffer)
__global__ __launch_bounds__(256) void k_denom(const int* __restrict__ ei,
                                               const unsigned* __restrict__ lmax,
                                               float* __restrict__ logits,
                                               float* __restrict__ denom, int E, int N) {
    int e = blockIdx.x * blockDim.x + threadIdx.x;
    int E2 = E + N;
    if (e >= E2) return;
    int d = (e < E) ? ei[E + e] : (e - E);
    #pragma unroll
    for (int h = 0; h < HH; ++h) {
        float m = dec_f32(lmax[d * HH + h]);
        float ex = __expf(logits[(size_t)e * HH + h] - m);
        logits[(size_t)e * HH + h] = ex;
        atomicAdd(&denom[d * HH + h], ex);
    }
}

// one wave per edge: out_acc[dst] += alpha * xs[src]  (192 lanes-atomics/edge)
__global__ __launch_bounds__(256) void k_scatter(const float* __restrict__ xs,
                                                 const int* __restrict__ ei,
                                                 const float* __restrict__ exbuf,
                                                 const float* __restrict__ denom,
                                                 float* __restrict__ out_acc, int E, int N) {
    long long gt = (long long)blockIdx.x * blockDim.x + threadIdx.x;
    int w = (int)(gt >> 6);
    int lane = threadIdx.x & 63;
    int E2 = E + N;
    if (w >= E2) return;
    int s, d;
    if (w < E) { s = ei[w]; d = ei[E + w]; } else { s = d = w - E; }
    size_t sb = (size_t)s * HC, db = (size_t)d * HC;
    #pragma unroll
    for (int h = 0; h < HH; ++h) {
        float alpha = exbuf[(size_t)w * HH + h] / denom[d * HH + h];
        float v = alpha * xs[sb + h * CC + lane];
        atomicAdd(&out_acc[db + h * CC + lane], v);
    }
}

// fused: (+gat_bias) @ w1 + b1, LN1(x+.), @ w2 + b2, LN2(lin+.)
__global__ __launch_bounds__(256) void k_mlp(const float* __restrict__ out_acc,
                                             const float* __restrict__ gat_bias,
                                             const float* __restrict__ x,
                                             const float* __restrict__ w1,
                                             const float* __restrict__ b1,
                                             const float* __restrict__ g1,
                                             const float* __restrict__ be1,
                                             const float* __restrict__ w2,
                                             const float* __restrict__ b2,
                                             const float* __restrict__ g2,
                                             const float* __restrict__ be2,
                                             float* __restrict__ out, int N) {
    __shared__ float w1l[HC * CC];   // 48 KB
    __shared__ float w2l[CC * CC];   // 16 KB
    for (int i = threadIdx.x; i < HC * CC; i += 256) w1l[i] = w1[i];
    for (int i = threadIdx.x; i < CC * CC; i += 256) w2l[i] = w2[i];
    __syncthreads();
    int lane = threadIdx.x & 63;
    int wid  = threadIdx.x >> 6;
    float b1v = b1[lane], g1v = g1[lane], be1v = be1[lane];
    float b2v = b2[lane], g2v = g2[lane], be2v = be2[lane];
    float gb0 = gat_bias[0 * CC + lane], gb1 = gat_bias[1 * CC + lane], gb2 = gat_bias[2 * CC + lane];
    for (int n = blockIdx.x * 4 + wid; n < N; n += gridDim.x * 4) {
        size_t base = (size_t)n * HC;
        float r0 = out_acc[base + 0 * CC + lane] + gb0;
        float r1 = out_acc[base + 1 * CC + lane] + gb1;
        float r2 = out_acc[base + 2 * CC + lane] + gb2;
        float acc = b1v;
        #pragma unroll
        for (int k = 0; k < CC; ++k) {
            float v0 = __shfl(r0, k, 64);
            float v1 = __shfl(r1, k, 64);
            float v2 = __shfl(r2, k, 64);
            acc += v0 * w1l[(0 * CC + k) * CC + lane]
                 + v1 * w1l[(1 * CC + k) * CC + lane]
                 + v2 * w1l[(2 * CC + k) * CC + lane];
        }
        float y = x[(size_t)n * DIN + lane] + acc;
        float m = wave_sum(y) * (1.0f / CC);
        float ym = y - m;
        float var = wave_sum(ym * ym) * (1.0f / CC);
        float h1 = ym * rsqrtf(var + LN_EPS) * g1v + be1v;
        float acc2 = b2v;
        #pragma unroll
        for (int k = 0; k < CC; ++k) {
            float hv = __shfl(h1, k, 64);
            acc2 += hv * w2l[k * CC + lane];
        }
        float z = acc2 + h1;
        float m2 = wave_sum(z) * (1.0f / CC);
        float zm = z - m2;
        float v2s = wave_sum(zm * zm) * (1.0f / CC);
        out[(size_t)n * CC + lane] = zm * rsqrtf(v2s + LN_EPS) * g2v + be2v;
    }
}

extern "C" void kernel_launch(void* const* d_in, const int* in_sizes, int n_in,
                              void* d_out, int out_size, void* d_ws, size_t ws_size,
                              hipStream_t stream) {
    const float* x          = (const float*)d_in[0];
    const float* edge_attr  = (const float*)d_in[1];
    const float* lin_w      = (const float*)d_in[2];
    const float* att_src    = (const float*)d_in[3];
    const float* att_dst    = (const float*)d_in[4];
    const float* lin_edge_w = (const float*)d_in[5];
    const float* att_edge   = (const float*)d_in[6];
    const float* gat_bias   = (const float*)d_in[7];
    const float* w1         = (const float*)d_in[8];
    const float* b1         = (const float*)d_in[9];
    const float* ln1_g      = (const float*)d_in[10];
    const float* ln1_b      = (const float*)d_in[11];
    const float* w2         = (const float*)d_in[12];
    const float* b2         = (const float*)d_in[13];
    const float* ln2_g      = (const float*)d_in[14];
    const float* ln2_b      = (const float*)d_in[15];
    const int*   ei         = (const int*)d_in[16];
    float* out = (float*)d_out;

    const int N  = in_sizes[0] / DIN;
    const int E  = in_sizes[1] / ED;
    const int E2 = E + N;

    char* ws = (char*)d_ws;
    size_t off = 0;
    auto alloc = [&](size_t bytes) {
        size_t o = off;
        off = (off + bytes + 255) & ~(size_t)255;
        return o;
    };
    // zeroed region first (single memset)
    float*    out_acc  = (float*)(ws + alloc((size_t)N * HC * 4));
    float*    attr_sum = (float*)(ws + alloc((size_t)N * ED * 4));
    float*    cnt      = (float*)(ws + alloc((size_t)N * 4));
    unsigned* lmax     = (unsigned*)(ws + alloc((size_t)N * HH * 4));
    float*    denom    = (float*)(ws + alloc((size_t)N * HH * 4));
    size_t zero_bytes = off;
    // fully-overwritten region
    float* xs     = (float*)(ws + alloc((size_t)N * HC * 4));
    float* logits = (float*)(ws + alloc((size_t)E2 * HH * 4));
    float* a_srcb = (float*)(ws + alloc((size_t)N * HH * 4));
    float* a_dstb = (float*)(ws + alloc((size_t)N * HH * 4));
    float* we     = (float*)(ws + alloc(ED * HH * 4));
    (void)ws_size; (void)n_in; (void)out_size;

    hipMemsetAsync(d_ws, 0, zero_bytes, stream);

    k_we<<<1, 64, 0, stream>>>(lin_edge_w, att_edge, we);
    k_edge_accum<<<(E + 255) / 256, 256, 0, stream>>>(edge_attr, ei, attr_sum, cnt, E);
    k_xs<<<(N + 3) / 4, 256, 0, stream>>>(x, lin_w, att_src, att_dst, xs, a_srcb, a_dstb, N);
    k_loop_attr<<<(N + 255) / 256, 256, 0, stream>>>(attr_sum, cnt, N);
    k_logits<<<(E2 + 255) / 256, 256, 0, stream>>>(edge_attr, attr_sum, ei, a_srcb, a_dstb,
                                                   we, logits, lmax, E, N);
    k_denom<<<(E2 + 255) / 256, 256, 0, stream>>>(ei, lmax, logits, denom, E, N);
    {
        long long threads = (long long)E2 * 64;
        int blocks = (int)((threads + 255) / 256);
        k_scatter<<<blocks, 256, 0, stream>>>(xs, ei, logits, denom, out_acc, E, N);
    }
    k_mlp<<<(N + 3) / 4, 256, 0, stream>>>(out_acc, gat_bias, x, w1, b1, ln1_g, ln1_b,
                                           w2, b2, ln2_g, ln2_b, out, N);
}

// Round 2
// 1158.622 us; speedup vs baseline: 1.4368x; 1.4368x over previous
//
#include <hip/hip_runtime.h>

// GraphTransformerBlock2: GATConv(H=3,C=64, edge_dim=5, self-loops w/ mean fill)
// -> linear1 -> LN(x + .) -> linear2 -> LN(lin + .)
// All float32. edge_index int32, layout (2,E) row-major: src=ei[0:E], dst=ei[E:2E].
//
// R1: CSR-based aggregation. Replaces atomic scatter (653 MB atomic writes) +
// logits/denom passes (5.1M atomics) with: degree count -> scan -> payload fill
// -> per-dst gather (register softmax + accumulate, no atomics).

#define HH 3
#define CC 64
#define DIN 64
#define ED 5
#define HC (HH*CC)          // 192
#define NEG_SLOPE 0.2f
#define LN_EPS 1e-5f

__device__ __forceinline__ float wave_sum(float v) {
    #pragma unroll
    for (int o = 32; o; o >>= 1) v += __shfl_xor(v, o, 64);
    return v;
}
__device__ __forceinline__ float leaky(float l) {
    return (l >= 0.f) ? l : NEG_SLOPE * l;
}

// we[d][h] = sum_c lin_edge_w[d, h*64+c] * att_edge[h, c]   (5x3)
__global__ __launch_bounds__(64) void k_we(const float* __restrict__ lin_edge_w,
                                           const float* __restrict__ att_edge,
                                           float* __restrict__ we) {
    int t = threadIdx.x;
    if (t >= ED * HH) return;
    int d = t / HH, h = t % HH;
    float s = 0.f;
    for (int c = 0; c < CC; ++c)
        s += lin_edge_w[d * HC + h * CC + c] * att_edge[h * CC + c];
    we[d * HH + h] = s;
}

// per-dst sums of edge_attr (self-loop mean) + int in-degree
__global__ __launch_bounds__(256) void k_edge_accum(const float* __restrict__ ea,
                                                    const int* __restrict__ ei,
                                                    float* __restrict__ attr_sum,
                                                    int* __restrict__ icnt, int E) {
    int e = blockIdx.x * blockDim.x + threadIdx.x;
    if (e >= E) return;
    int d = ei[E + e];
    #pragma unroll
    for (int j = 0; j < ED; ++j) atomicAdd(&attr_sum[d * ED + j], ea[(size_t)e * ED + j]);
    atomicAdd(&icnt[d], 1);
}

// xs = x @ lin_w  (N x 192), plus a_src[n,h], a_dst[n,h]
__global__ __launch_bounds__(256) void k_xs(const float* __restrict__ x,
                                            const float* __restrict__ lin_w,
                                            const float* __restrict__ att_src,
                                            const float* __restrict__ att_dst,
                                            float* __restrict__ xs,
                                            float* __restrict__ a_src,
                                            float* __restrict__ a_dst, int N) {
    __shared__ float wl[DIN * HC];                 // 48 KB
    for (int i = threadIdx.x; i < DIN * HC; i += 256) wl[i] = lin_w[i];
    __syncthreads();
    int lane = threadIdx.x & 63;
    int wid  = threadIdx.x >> 6;
    float as0 = att_src[0 * CC + lane], as1 = att_src[1 * CC + lane], as2 = att_src[2 * CC + lane];
    float ad0 = att_dst[0 * CC + lane], ad1 = att_dst[1 * CC + lane], ad2 = att_dst[2 * CC + lane];
    for (int n = blockIdx.x * 4 + wid; n < N; n += gridDim.x * 4) {
        float xv = x[(size_t)n * DIN + lane];
        float a0 = 0.f, a1 = 0.f, a2 = 0.f;
        #pragma unroll
        for (int d = 0; d < DIN; ++d) {
            float xd = __shfl(xv, d, 64);
            a0 += xd * wl[d * HC + 0 * CC + lane];
            a1 += xd * wl[d * HC + 1 * CC + lane];
            a2 += xd * wl[d * HC + 2 * CC + lane];
        }
        size_t base = (size_t)n * HC;
        xs[base + 0 * CC + lane] = a0;
        xs[base + 1 * CC + lane] = a1;
        xs[base + 2 * CC + lane] = a2;
        float s0 = wave_sum(a0 * as0), s1 = wave_sum(a1 * as1), s2 = wave_sum(a2 * as2);
        float d0 = wave_sum(a0 * ad0), d1 = wave_sum(a1 * ad1), d2 = wave_sum(a2 * ad2);
        if (lane == 0) {
            a_src[n * HH + 0] = s0; a_src[n * HH + 1] = s1; a_src[n * HH + 2] = s2;
            a_dst[n * HH + 0] = d0; a_dst[n * HH + 1] = d1; a_dst[n * HH + 2] = d2;
        }
    }
}

// exclusive scan of icnt -> off[0..N] (off[N]=E), and cursor[n]=off[n]
__global__ __launch_bounds__(1024) void k_scan(const int* __restrict__ icnt,
                                               int* __restrict__ off,
                                               int* __restrict__ cursor, int N) {
    __shared__ int sums[1024];
    int t = threadIdx.x;
    int chunk = (N + 1023) / 1024;
    int b = t * chunk;
    int e = min(b + chunk, N);
    int s = 0;
    for (int i = b; i < e; ++i) s += icnt[i];
    sums[t] = s;
    __syncthreads();
    for (int d = 1; d < 1024; d <<= 1) {
        int v = (t >= d) ? sums[t - d] : 0;
        __syncthreads();
        sums[t] += v;
        __syncthreads();
    }
    int excl = (t == 0) ? 0 : sums[t - 1];
    for (int i = b; i < e; ++i) {
        off[i] = excl;
        cursor[i] = excl;
        excl += icnt[i];
    }
    if (t == 1023) off[N] = sums[1023];
}

// payload[pos] = {lp0, lp1, lp2, src}  in CSR (dst-sorted) order
// lp[h] = a_src[src][h] + sum_j ea[e][j]*we[j][h]
__global__ __launch_bounds__(256) void k_fill(const float* __restrict__ ea,
                                              const int* __restrict__ ei,
                                              const float* __restrict__ a_src,
                                              const float* __restrict__ we,
                                              int* __restrict__ cursor,
                                              float4* __restrict__ payload, int E) {
    int e = blockIdx.x * blockDim.x + threadIdx.x;
    if (e >= E) return;
    int s = ei[e], d = ei[E + e];
    float attr[ED];
    #pragma unroll
    for (int j = 0; j < ED; ++j) attr[j] = ea[(size_t)e * ED + j];
    float lp[HH];
    #pragma unroll
    for (int h = 0; h < HH; ++h) {
        float aeg = 0.f;
        #pragma unroll
        for (int j = 0; j < ED; ++j) aeg += attr[j] * we[j * HH + h];
        lp[h] = a_src[s * HH + h] + aeg;
    }
    int pos = atomicAdd(&cursor[d], 1);
    payload[pos] = make_float4(lp[0], lp[1], lp[2], __int_as_float(s));
}

// one wave per dst node: segment softmax + weighted gather, all in registers
__global__ __launch_bounds__(256) void k_gat(const float* __restrict__ xs,
                                             const float* __restrict__ a_src,
                                             const float* __restrict__ a_dst,
                                             const float* __restrict__ attr_sum,
                                             const int* __restrict__ icnt,
                                             const float* __restrict__ we,
                                             const int* __restrict__ off,
                                             const float4* __restrict__ payload,
                                             float* __restrict__ out_acc, int N) {
    int lane = threadIdx.x & 63;
    int wid  = threadIdx.x >> 6;
    for (int n = blockIdx.x * 4 + wid; n < N; n += gridDim.x * 4) {
        int beg = off[n], end = off[n + 1];
        int deg = end - beg;
        float ad0 = a_dst[n * HH + 0], ad1 = a_dst[n * HH + 1], ad2 = a_dst[n * HH + 2];
        // self-loop logit (fill_value='mean' edge attr)
        float c = fmaxf((float)icnt[n], 1.0f);
        float la[ED];
        #pragma unroll
        for (int j = 0; j < ED; ++j) la[j] = attr_sum[n * ED + j] / c;
        float sl0, sl1, sl2;
        {
            float aeg0 = 0.f, aeg1 = 0.f, aeg2 = 0.f;
            #pragma unroll
            for (int j = 0; j < ED; ++j) {
                aeg0 += la[j] * we[j * HH + 0];
                aeg1 += la[j] * we[j * HH + 1];
                aeg2 += la[j] * we[j * HH + 2];
            }
            sl0 = leaky(a_src[n * HH + 0] + aeg0 + ad0);
            sl1 = leaky(a_src[n * HH + 1] + aeg1 + ad1);
            sl2 = leaky(a_src[n * HH + 2] + aeg2 + ad2);
        }
        // pass A: lane-parallel max over segment
        float m0 = sl0, m1 = sl1, m2 = sl2;
        for (int i = lane; i < deg; i += 64) {
            float4 p = payload[beg + i];
            m0 = fmaxf(m0, leaky(p.x + ad0));
            m1 = fmaxf(m1, leaky(p.y + ad1));
            m2 = fmaxf(m2, leaky(p.z + ad2));
        }
        #pragma unroll
        for (int o = 32; o; o >>= 1) {
            m0 = fmaxf(m0, __shfl_xor(m0, o, 64));
            m1 = fmaxf(m1, __shfl_xor(m1, o, 64));
            m2 = fmaxf(m2, __shfl_xor(m2, o, 64));
        }
        // pass B: serial accumulate (self-loop first)
        size_t nb = (size_t)n * HC;
        float e0 = __expf(sl0 - m0), e1 = __expf(sl1 - m1), e2 = __expf(sl2 - m2);
        float den0 = e0, den1 = e1, den2 = e2;
        float acc0 = e0 * xs[nb + 0 * CC + lane];
        float acc1 = e1 * xs[nb + 1 * CC + lane];
        float acc2 = e2 * xs[nb + 2 * CC + lane];
        if (deg > 0) {
            float4 p = payload[beg];
            for (int i = 0; i < deg; ++i) {
                float4 pn;
                if (i + 1 < deg) pn = payload[beg + i + 1];
                float w0 = __expf(leaky(p.x + ad0) - m0);
                float w1 = __expf(leaky(p.y + ad1) - m1);
                float w2 = __expf(leaky(p.z + ad2) - m2);
                int s = __float_as_int(p.w);
                size_t sb = (size_t)s * HC;
                float x0 = xs[sb + 0 * CC + lane];
                float x1 = xs[sb + 1 * CC + lane];
                float x2 = xs[sb + 2 * CC + lane];
                den0 += w0; den1 += w1; den2 += w2;
                acc0 += w0 * x0; acc1 += w1 * x1; acc2 += w2 * x2;
                p = pn;
            }
        }
        out_acc[nb + 0 * CC + lane] = acc0 / den0;
        out_acc[nb + 1 * CC + lane] = acc1 / den1;
        out_acc[nb + 2 * CC + lane] = acc2 / den2;
    }
}

// fused: (+gat_bias) @ w1 + b1, LN1(x+.), @ w2 + b2, LN2(lin+.)
__global__ __launch_bounds__(256) void k_mlp(const float* __restrict__ out_acc,
                                             const float* __restrict__ gat_bias,
                                             const float* __restrict__ x,
                                             const float* __restrict__ w1,
                                             const float* __restrict__ b1,
                                             const float* __restrict__ g1,
                                             const float* __restrict__ be1,
                                             const float* __restrict__ w2,
                                             const float* __restrict__ b2,
                                             const float* __restrict__ g2,
                                             const float* __restrict__ be2,
                                             float* __restrict__ out, int N) {
    __shared__ float w1l[HC * CC];   // 48 KB
    __shared__ float w2l[CC * CC];   // 16 KB
    for (int i = threadIdx.x; i < HC * CC; i += 256) w1l[i] = w1[i];
    for (int i = threadIdx.x; i < CC * CC; i += 256) w2l[i] = w2[i];
    __syncthreads();
    int lane = threadIdx.x & 63;
    int wid  = threadIdx.x >> 6;
    float b1v = b1[lane], g1v = g1[lane], be1v = be1[lane];
    float b2v = b2[lane], g2v = g2[lane], be2v = be2[lane];
    float gb0 = gat_bias[0 * CC + lane], gb1 = gat_bias[1 * CC + lane], gb2 = gat_bias[2 * CC + lane];
    for (int n = blockIdx.x * 4 + wid; n < N; n += gridDim.x * 4) {
        size_t base = (size_t)n * HC;
        float r0 = out_acc[base + 0 * CC + lane] + gb0;
        float r1 = out_acc[base + 1 * CC + lane] + gb1;
        float r2 = out_acc[base + 2 * CC + lane] + gb2;
        float acc = b1v;
        #pragma unroll
        for (int k = 0; k < CC; ++k) {
            float v0 = __shfl(r0, k, 64);
            float v1 = __shfl(r1, k, 64);
            float v2 = __shfl(r2, k, 64);
            acc += v0 * w1l[(0 * CC + k) * CC + lane]
                 + v1 * w1l[(1 * CC + k) * CC + lane]
                 + v2 * w1l[(2 * CC + k) * CC + lane];
        }
        float y = x[(size_t)n * DIN + lane] + acc;
        float m = wave_sum(y) * (1.0f / CC);
        float ym = y - m;
        float var = wave_sum(ym * ym) * (1.0f / CC);
        float h1 = ym * rsqrtf(var + LN_EPS) * g1v + be1v;
        float acc2 = b2v;
        #pragma unroll
        for (int k = 0; k < CC; ++k) {
            float hv = __shfl(h1, k, 64);
            acc2 += hv * w2l[k * CC + lane];
        }
        float z = acc2 + h1;
        float m2 = wave_sum(z) * (1.0f / CC);
        float zm = z - m2;
        float v2s = wave_sum(zm * zm) * (1.0f / CC);
        out[(size_t)n * CC + lane] = zm * rsqrtf(v2s + LN_EPS) * g2v + be2v;
    }
}

extern "C" void kernel_launch(void* const* d_in, const int* in_sizes, int n_in,
                              void* d_out, int out_size, void* d_ws, size_t ws_size,
                              hipStream_t stream) {
    const float* x          = (const float*)d_in[0];
    const float* edge_attr  = (const float*)d_in[1];
    const float* lin_w      = (const float*)d_in[2];
    const float* att_src    = (const float*)d_in[3];
    const float* att_dst    = (const float*)d_in[4];
    const float* lin_edge_w = (const float*)d_in[5];
    const float* att_edge   = (const float*)d_in[6];
    const float* gat_bias   = (const float*)d_in[7];
    const float* w1         = (const float*)d_in[8];
    const float* b1         = (const float*)d_in[9];
    const float* ln1_g      = (const float*)d_in[10];
    const float* ln1_b      = (const float*)d_in[11];
    const float* w2         = (const float*)d_in[12];
    const float* b2         = (const float*)d_in[13];
    const float* ln2_g      = (const float*)d_in[14];
    const float* ln2_b      = (const float*)d_in[15];
    const int*   ei         = (const int*)d_in[16];
    float* out = (float*)d_out;

    const int N = in_sizes[0] / DIN;
    const int E = in_sizes[1] / ED;

    char* ws = (char*)d_ws;
    size_t off_b = 0;
    auto alloc = [&](size_t bytes) {
        size_t o = off_b;
        off_b = (off_b + bytes + 255) & ~(size_t)255;
        return o;
    };
    // zeroed region first (single memset)
    float* attr_sum = (float*)(ws + alloc((size_t)N * ED * 4));
    int*   icnt     = (int*)(ws + alloc((size_t)N * 4));
    size_t zero_bytes = off_b;
    // fully-overwritten region
    float*  xs      = (float*)(ws + alloc((size_t)N * HC * 4));
    float*  out_acc = (float*)(ws + alloc((size_t)N * HC * 4));
    float*  a_srcb  = (float*)(ws + alloc((size_t)N * HH * 4));
    float*  a_dstb  = (float*)(ws + alloc((size_t)N * HH * 4));
    int*    offb    = (int*)(ws + alloc((size_t)(N + 1) * 4));
    int*    cursor  = (int*)(ws + alloc((size_t)N * 4));
    float4* payload = (float4*)(ws + alloc((size_t)E * 16));
    float*  we      = (float*)(ws + alloc(ED * HH * 4));
    (void)ws_size; (void)n_in; (void)out_size;

    hipMemsetAsync(d_ws, 0, zero_bytes, stream);

    k_we<<<1, 64, 0, stream>>>(lin_edge_w, att_edge, we);
    k_edge_accum<<<(E + 255) / 256, 256, 0, stream>>>(edge_attr, ei, attr_sum, icnt, E);
    k_xs<<<(N + 3) / 4, 256, 0, stream>>>(x, lin_w, att_src, att_dst, xs, a_srcb, a_dstb, N);
    k_scan<<<1, 1024, 0, stream>>>(icnt, offb, cursor, N);
    k_fill<<<(E + 255) / 256, 256, 0, stream>>>(edge_attr, ei, a_srcb, we, cursor, payload, E);
    k_gat<<<(N + 3) / 4, 256, 0, stream>>>(xs, a_srcb, a_dstb, attr_sum, icnt, we,
                                           offb, payload, out_acc, N);
    k_mlp<<<(N + 3) / 4, 256, 0, stream>>>(out_acc, gat_bias, x, w1, b1, ln1_g, ln1_b,
                                           w2, b2, ln2_g, ln2_b, out, N);
}

// Round 3
// 360.903 us; speedup vs baseline: 4.6126x; 3.2103x over previous
//
#include <hip/hip_runtime.h>

// GraphTransformerBlock2: GATConv(H=3,C=64, edge_dim=5, self-loops w/ mean fill)
// -> linear1 -> LN(x + .) -> linear2 -> LN(lin + .)
// All float32 I/O. edge_index int32 (2,E): src=ei[0:E], dst=ei[E:2E].
//
// R2: bf16 MFMA for the two dense GEMM chains (k_xs, k_mlp), f32 accumulate.
//     Frag safety: A uses [lane&15][ (lane>>4)*8+j ], B uses the SAME k-index
//     formula -> any HW k-permutation cancels (sigma-argument); C/D layout
//     (col=lane&15, row=(lane>>4)*4+reg) is HW-verified.
//     Also: removed 4.8M float atomics (attr mean folded into per-edge ae sums).

#define HH 3
#define CC 64
#define DIN 64
#define ED 5
#define HC 192
#define NEG_SLOPE 0.2f
#define LN_EPS 1e-5f

typedef __attribute__((ext_vector_type(8))) short bf16x8;
typedef __attribute__((ext_vector_type(4))) float f32x4;

__device__ __forceinline__ float leaky(float l) { return (l >= 0.f) ? l : NEG_SLOPE * l; }

__device__ __forceinline__ unsigned short f2bf(float f) {
    unsigned u = __float_as_uint(f);
    unsigned r = (u + 0x7FFFu + ((u >> 16) & 1u)) >> 16;   // RNE
    return (unsigned short)r;
}

__device__ __forceinline__ bf16x8 pack8(float4 a, float4 b) {
    bf16x8 r;
    r[0] = (short)f2bf(a.x); r[1] = (short)f2bf(a.y);
    r[2] = (short)f2bf(a.z); r[3] = (short)f2bf(a.w);
    r[4] = (short)f2bf(b.x); r[5] = (short)f2bf(b.y);
    r[6] = (short)f2bf(b.z); r[7] = (short)f2bf(b.w);
    return r;
}

// ---------- prep: bf16 transposed weights + folded bias + we ----------
// linwt[c][k] = lin_w[k][c]  (192x64 bf16)      c<192,k<64
// w1t[c][k]   = w1[k][c]     (64x192 bf16)      c<64, k<192
// w2t[c][k]   = w2[k][c]     (64x64  bf16)
// b1p[c]      = b1[c] + sum_k gat_bias[k] w1[k][c]
// we[d][h]    = sum_c lin_edge_w[d, h*64+c] * att_edge[h,c]
#define PREP_TOT (HC*DIN + DIN*HC + CC*CC + CC + ED*HH)
__global__ __launch_bounds__(256) void k_prep(const float* __restrict__ lin_w,
                                              const float* __restrict__ w1,
                                              const float* __restrict__ w2,
                                              const float* __restrict__ b1,
                                              const float* __restrict__ gat_bias,
                                              const float* __restrict__ lin_edge_w,
                                              const float* __restrict__ att_edge,
                                              unsigned short* __restrict__ linwt,
                                              unsigned short* __restrict__ w1t,
                                              unsigned short* __restrict__ w2t,
                                              float* __restrict__ b1p,
                                              float* __restrict__ we) {
    for (int i = blockIdx.x * 256 + threadIdx.x; i < PREP_TOT; i += gridDim.x * 256) {
        if (i < HC * DIN) {                       // linwt: c = i>>6, k = i&63
            int c = i >> 6, k = i & 63;
            linwt[i] = f2bf(lin_w[k * HC + c]);
        } else if (i < 2 * HC * DIN) {            // w1t: c = j/192, k = j%192
            int j = i - HC * DIN;
            int c = j / HC, k = j - c * HC;
            w1t[j] = f2bf(w1[k * CC + c]);
        } else if (i < 2 * HC * DIN + CC * CC) {  // w2t
            int j = i - 2 * HC * DIN;
            int c = j >> 6, k = j & 63;
            w2t[j] = f2bf(w2[k * CC + c]);
        } else if (i < 2 * HC * DIN + CC * CC + CC) {
            int c = i - (2 * HC * DIN + CC * CC);
            float s = b1[c];
            for (int k = 0; k < HC; ++k) s += gat_bias[k] * w1[k * CC + c];
            b1p[c] = s;
        } else {
            int q = i - (2 * HC * DIN + CC * CC + CC);
            int d = q / HH, h = q - d * HH;
            float s = 0.f;
            for (int c = 0; c < CC; ++c)
                s += lin_edge_w[d * HC + h * CC + c] * att_edge[h * CC + c];
            we[q] = s;
        }
    }
}

// ---------- in-degree count ----------
__global__ __launch_bounds__(256) void k_cnt(const int* __restrict__ ei,
                                             int* __restrict__ icnt, int E) {
    int e = blockIdx.x * blockDim.x + threadIdx.x;
    if (e >= E) return;
    atomicAdd(&icnt[ei[E + e]], 1);
}

// ---------- xs = x @ lin_w (MFMA) + a_src/a_dst ----------
__global__ __launch_bounds__(256) void k_xs(const float* __restrict__ x,
                                            const unsigned short* __restrict__ linwt,
                                            const float* __restrict__ att_src,
                                            const float* __restrict__ att_dst,
                                            float* __restrict__ xs,
                                            float* __restrict__ a_src,
                                            float* __restrict__ a_dst, int N) {
    int lane = threadIdx.x & 63, w = threadIdx.x >> 6;
    int l15 = lane & 15, kg = (lane >> 4) * 8;
    int nb = blockIdx.x * 64;
    int arow = nb + w * 16 + l15;
    int arow_c = min(arow, N - 1);

    f32x4 acc[12];
    #pragma unroll
    for (int ct = 0; ct < 12; ++ct) acc[ct] = (f32x4){0.f, 0.f, 0.f, 0.f};

    #pragma unroll
    for (int k0 = 0; k0 < DIN; k0 += 32) {
        const float* ap = x + (size_t)arow_c * DIN + k0 + kg;
        float4 a0 = *(const float4*)ap;
        float4 a1 = *(const float4*)(ap + 4);
        bf16x8 af = pack8(a0, a1);
        #pragma unroll
        for (int ct = 0; ct < 12; ++ct) {
            bf16x8 bf = *(const bf16x8*)(linwt + (size_t)(ct * 16 + l15) * DIN + k0 + kg);
            acc[ct] = __builtin_amdgcn_mfma_f32_16x16x32_bf16(af, bf, acc[ct], 0, 0, 0);
        }
    }

    float asv[12], adv[12];
    #pragma unroll
    for (int ct = 0; ct < 12; ++ct) {
        int c = ct * 16 + l15;
        asv[ct] = att_src[c]; adv[ct] = att_dst[c];
    }

    int rbase = nb + w * 16 + (lane >> 4) * 4;
    #pragma unroll
    for (int j = 0; j < 4; ++j) {
        int r = rbase + j;
        bool ok = r < N;
        float ps0 = 0.f, ps1 = 0.f, ps2 = 0.f, pd0 = 0.f, pd1 = 0.f, pd2 = 0.f;
        #pragma unroll
        for (int ct = 0; ct < 12; ++ct) {
            float v = acc[ct][j];
            if (ok) xs[(size_t)r * HC + ct * 16 + l15] = v;
            float s = v * asv[ct], d = v * adv[ct];
            if (ct < 4)      { ps0 += s; pd0 += d; }
            else if (ct < 8) { ps1 += s; pd1 += d; }
            else             { ps2 += s; pd2 += d; }
        }
        #pragma unroll
        for (int o = 1; o < 16; o <<= 1) {
            ps0 += __shfl_xor(ps0, o, 64); pd0 += __shfl_xor(pd0, o, 64);
            ps1 += __shfl_xor(ps1, o, 64); pd1 += __shfl_xor(pd1, o, 64);
            ps2 += __shfl_xor(ps2, o, 64); pd2 += __shfl_xor(pd2, o, 64);
        }
        if (ok && l15 == 0) {
            a_src[r * HH + 0] = ps0; a_src[r * HH + 1] = ps1; a_src[r * HH + 2] = ps2;
            a_dst[r * HH + 0] = pd0; a_dst[r * HH + 1] = pd1; a_dst[r * HH + 2] = pd2;
        }
    }
}

// ---------- exclusive scan of icnt -> off[0..N], cursor ----------
__global__ __launch_bounds__(1024) void k_scan(const int* __restrict__ icnt,
                                               int* __restrict__ off,
                                               int* __restrict__ cursor, int N) {
    __shared__ int sums[1024];
    int t = threadIdx.x;
    int chunk = (N + 1023) / 1024;
    int b = t * chunk;
    int e = min(b + chunk, N);
    int s = 0;
    for (int i = b; i < e; ++i) s += icnt[i];
    sums[t] = s;
    __syncthreads();
    for (int d = 1; d < 1024; d <<= 1) {
        int v = (t >= d) ? sums[t - d] : 0;
        __syncthreads();
        sums[t] += v;
        __syncthreads();
    }
    int excl = (t == 0) ? 0 : sums[t - 1];
    for (int i = b; i < e; ++i) {
        off[i] = excl;
        cursor[i] = excl;
        excl += icnt[i];
    }
    if (t == 1023) off[N] = sums[1023];
}

// ---------- payload fill (CSR order): p0={lp0,lp1,lp2,src}, ae={ae0,ae1,ae2,0} ----------
__global__ __launch_bounds__(256) void k_fill(const float* __restrict__ ea,
                                              const int* __restrict__ ei,
                                              const float* __restrict__ a_src,
                                              const float* __restrict__ we,
                                              int* __restrict__ cursor,
                                              float4* __restrict__ payload,
                                              float4* __restrict__ paylae, int E) {
    int e = blockIdx.x * blockDim.x + threadIdx.x;
    if (e >= E) return;
    int s = ei[e], d = ei[E + e];
    float attr[ED];
    #pragma unroll
    for (int j = 0; j < ED; ++j) attr[j] = ea[(size_t)e * ED + j];
    float aeh[HH];
    #pragma unroll
    for (int h = 0; h < HH; ++h) {
        float a = 0.f;
        #pragma unroll
        for (int j = 0; j < ED; ++j) a += attr[j] * we[j * HH + h];
        aeh[h] = a;
    }
    int pos = atomicAdd(&cursor[d], 1);
    payload[pos] = make_float4(a_src[s * HH + 0] + aeh[0],
                               a_src[s * HH + 1] + aeh[1],
                               a_src[s * HH + 2] + aeh[2], __int_as_float(s));
    paylae[pos] = make_float4(aeh[0], aeh[1], aeh[2], 0.f);
}

// ---------- per-dst segment softmax + weighted gather ----------
__global__ __launch_bounds__(256) void k_gat(const float* __restrict__ xs,
                                             const float* __restrict__ a_src,
                                             const float* __restrict__ a_dst,
                                             const int* __restrict__ off,
                                             const float4* __restrict__ payload,
                                             const float4* __restrict__ paylae,
                                             float* __restrict__ out_acc, int N) {
    int lane = threadIdx.x & 63;
    int wid  = threadIdx.x >> 6;
    for (int n = blockIdx.x * 4 + wid; n < N; n += gridDim.x * 4) {
        int beg = off[n], end = off[n + 1];
        int deg = end - beg;
        float ad0 = a_dst[n * HH + 0], ad1 = a_dst[n * HH + 1], ad2 = a_dst[n * HH + 2];
        float m0 = -1e30f, m1 = -1e30f, m2 = -1e30f;
        float s0 = 0.f, s1 = 0.f, s2 = 0.f;
        for (int i = lane; i < deg; i += 64) {
            float4 p = payload[beg + i];
            float4 q = paylae[beg + i];
            m0 = fmaxf(m0, leaky(p.x + ad0));
            m1 = fmaxf(m1, leaky(p.y + ad1));
            m2 = fmaxf(m2, leaky(p.z + ad2));
            s0 += q.x; s1 += q.y; s2 += q.z;
        }
        #pragma unroll
        for (int o = 32; o; o >>= 1) {
            m0 = fmaxf(m0, __shfl_xor(m0, o, 64));
            m1 = fmaxf(m1, __shfl_xor(m1, o, 64));
            m2 = fmaxf(m2, __shfl_xor(m2, o, 64));
            s0 += __shfl_xor(s0, o, 64);
            s1 += __shfl_xor(s1, o, 64);
            s2 += __shfl_xor(s2, o, 64);
        }
        float dc = fmaxf((float)deg, 1.0f);
        float sl0 = leaky(a_src[n * HH + 0] + ad0 + s0 / dc);
        float sl1 = leaky(a_src[n * HH + 1] + ad1 + s1 / dc);
        float sl2 = leaky(a_src[n * HH + 2] + ad2 + s2 / dc);
        m0 = fmaxf(m0, sl0); m1 = fmaxf(m1, sl1); m2 = fmaxf(m2, sl2);

        size_t nbse = (size_t)n * HC;
        float e0 = __expf(sl0 - m0), e1 = __expf(sl1 - m1), e2 = __expf(sl2 - m2);
        float den0 = e0, den1 = e1, den2 = e2;
        float acc0 = e0 * xs[nbse + 0 * CC + lane];
        float acc1 = e1 * xs[nbse + 1 * CC + lane];
        float acc2 = e2 * xs[nbse + 2 * CC + lane];
        if (deg > 0) {
            float4 p = payload[beg];
            for (int i = 0; i < deg; ++i) {
                float4 pn;
                if (i + 1 < deg) pn = payload[beg + i + 1];
                float w0 = __expf(leaky(p.x + ad0) - m0);
                float w1 = __expf(leaky(p.y + ad1) - m1);
                float w2 = __expf(leaky(p.z + ad2) - m2);
                int s = __float_as_int(p.w);
                size_t sb = (size_t)s * HC;
                float x0 = xs[sb + 0 * CC + lane];
                float x1 = xs[sb + 1 * CC + lane];
                float x2 = xs[sb + 2 * CC + lane];
                den0 += w0; den1 += w1; den2 += w2;
                acc0 += w0 * x0; acc1 += w1 * x1; acc2 += w2 * x2;
                p = pn;
            }
        }
        out_acc[nbse + 0 * CC + lane] = acc0 / den0;
        out_acc[nbse + 1 * CC + lane] = acc1 / den1;
        out_acc[nbse + 2 * CC + lane] = acc2 / den2;
    }
}

// ---------- fused MLP: GEMM1 -> LN1 -> GEMM2 -> LN2 (MFMA, in-reg LN) ----------
__global__ __launch_bounds__(256) void k_mlp(const float* __restrict__ out_acc,
                                             const unsigned short* __restrict__ w1t,
                                             const unsigned short* __restrict__ w2t,
                                             const float* __restrict__ b1p,
                                             const float* __restrict__ x,
                                             const float* __restrict__ g1,
                                             const float* __restrict__ be1,
                                             const float* __restrict__ b2,
                                             const float* __restrict__ g2,
                                             const float* __restrict__ be2,
                                             float* __restrict__ out, int N) {
    __shared__ unsigned short H1[64 * 72];   // [node-in-tile][feature] bf16, pad 72
    int lane = threadIdx.x & 63, w = threadIdx.x >> 6;
    int l15 = lane & 15, kg = (lane >> 4) * 8;
    int nb = blockIdx.x * 64;
    int arow = nb + w * 16 + l15;
    int arow_c = min(arow, N - 1);

    float c_b1[4], c_g1[4], c_be1[4], c_b2[4], c_g2[4], c_be2[4];
    #pragma unroll
    for (int ct = 0; ct < 4; ++ct) {
        int c = ct * 16 + l15;
        c_b1[ct] = b1p[c]; c_g1[ct] = g1[c]; c_be1[ct] = be1[c];
        c_b2[ct] = b2[c];  c_g2[ct] = g2[c]; c_be2[ct] = be2[c];
    }

    // GEMM1: [64 x 192] @ [192 x 64]
    f32x4 acc[4];
    #pragma unroll
    for (int ct = 0; ct < 4; ++ct) acc[ct] = (f32x4){0.f, 0.f, 0.f, 0.f};
    #pragma unroll
    for (int k0 = 0; k0 < HC; k0 += 32) {
        const float* ap = out_acc + (size_t)arow_c * HC + k0 + kg;
        float4 a0 = *(const float4*)ap;
        float4 a1 = *(const float4*)(ap + 4);
        bf16x8 af = pack8(a0, a1);
        #pragma unroll
        for (int ct = 0; ct < 4; ++ct) {
            bf16x8 bf = *(const bf16x8*)(w1t + (size_t)(ct * 16 + l15) * HC + k0 + kg);
            acc[ct] = __builtin_amdgcn_mfma_f32_16x16x32_bf16(af, bf, acc[ct], 0, 0, 0);
        }
    }

    // epilogue1: y = acc + b1' + x ; LN1 -> h1 (regs + LDS bf16)
    int rbase = nb + w * 16 + (lane >> 4) * 4;
    int rloc0 = w * 16 + (lane >> 4) * 4;
    float h1v[4][4];                         // [ct][j]
    float y[4][4];
    #pragma unroll
    for (int j = 0; j < 4; ++j) {
        int r = min(rbase + j, N - 1);
        #pragma unroll
        for (int ct = 0; ct < 4; ++ct)
            y[ct][j] = acc[ct][j] + c_b1[ct] + x[(size_t)r * DIN + ct * 16 + l15];
    }
    #pragma unroll
    for (int j = 0; j < 4; ++j) {
        float s = y[0][j] + y[1][j] + y[2][j] + y[3][j];
        #pragma unroll
        for (int o = 1; o < 16; o <<= 1) s += __shfl_xor(s, o, 64);
        float m = s * (1.0f / CC);
        float vs = 0.f;
        #pragma unroll
        for (int ct = 0; ct < 4; ++ct) { float d = y[ct][j] - m; vs += d * d; }
        #pragma unroll
        for (int o = 1; o < 16; o <<= 1) vs += __shfl_xor(vs, o, 64);
        float inv = rsqrtf(vs * (1.0f / CC) + LN_EPS);
        #pragma unroll
        for (int ct = 0; ct < 4; ++ct) {
            float h = (y[ct][j] - m) * inv * c_g1[ct] + c_be1[ct];
            h1v[ct][j] = h;
            H1[(rloc0 + j) * 72 + ct * 16 + l15] = f2bf(h);
        }
    }
    __syncthreads();

    // GEMM2: [64 x 64] @ [64 x 64]
    f32x4 acc2[4];
    #pragma unroll
    for (int ct = 0; ct < 4; ++ct) acc2[ct] = (f32x4){0.f, 0.f, 0.f, 0.f};
    #pragma unroll
    for (int k0 = 0; k0 < CC; k0 += 32) {
        bf16x8 af = *(const bf16x8*)&H1[(w * 16 + l15) * 72 + k0 + kg];
        #pragma unroll
        for (int ct = 0; ct < 4; ++ct) {
            bf16x8 bf = *(const bf16x8*)(w2t + (size_t)(ct * 16 + l15) * CC + k0 + kg);
            acc2[ct] = __builtin_amdgcn_mfma_f32_16x16x32_bf16(af, bf, acc2[ct], 0, 0, 0);
        }
    }

    // epilogue2: z = acc2 + b2 + h1 ; LN2 -> out
    #pragma unroll
    for (int j = 0; j < 4; ++j) {
        float z0 = acc2[0][j] + c_b2[0] + h1v[0][j];
        float z1 = acc2[1][j] + c_b2[1] + h1v[1][j];
        float z2 = acc2[2][j] + c_b2[2] + h1v[2][j];
        float z3 = acc2[3][j] + c_b2[3] + h1v[3][j];
        float s = z0 + z1 + z2 + z3;
        #pragma unroll
        for (int o = 1; o < 16; o <<= 1) s += __shfl_xor(s, o, 64);
        float m = s * (1.0f / CC);
        float d0 = z0 - m, d1 = z1 - m, d2 = z2 - m, d3 = z3 - m;
        float vs = d0 * d0 + d1 * d1 + d2 * d2 + d3 * d3;
        #pragma unroll
        for (int o = 1; o < 16; o <<= 1) vs += __shfl_xor(vs, o, 64);
        float inv = rsqrtf(vs * (1.0f / CC) + LN_EPS);
        int r = rbase + j;
        if (r < N) {
            out[(size_t)r * CC + 0 * 16 + l15] = d0 * inv * c_g2[0] + c_be2[0];
            out[(size_t)r * CC + 1 * 16 + l15] = d1 * inv * c_g2[1] + c_be2[1];
            out[(size_t)r * CC + 2 * 16 + l15] = d2 * inv * c_g2[2] + c_be2[2];
            out[(size_t)r * CC + 3 * 16 + l15] = d3 * inv * c_g2[3] + c_be2[3];
        }
    }
}

extern "C" void kernel_launch(void* const* d_in, const int* in_sizes, int n_in,
                              void* d_out, int out_size, void* d_ws, size_t ws_size,
                              hipStream_t stream) {
    const float* x          = (const float*)d_in[0];
    const float* edge_attr  = (const float*)d_in[1];
    const float* lin_w      = (const float*)d_in[2];
    const float* att_src    = (const float*)d_in[3];
    const float* att_dst    = (const float*)d_in[4];
    const float* lin_edge_w = (const float*)d_in[5];
    const float* att_edge   = (const float*)d_in[6];
    const float* gat_bias   = (const float*)d_in[7];
    const float* w1         = (const float*)d_in[8];
    const float* b1         = (const float*)d_in[9];
    const float* ln1_g      = (const float*)d_in[10];
    const float* ln1_b      = (const float*)d_in[11];
    const float* w2         = (const float*)d_in[12];
    const float* b2         = (const float*)d_in[13];
    const float* ln2_g      = (const float*)d_in[14];
    const float* ln2_b      = (const float*)d_in[15];
    const int*   ei         = (const int*)d_in[16];
    float* out = (float*)d_out;

    const int N = in_sizes[0] / DIN;
    const int E = in_sizes[1] / ED;

    char* ws = (char*)d_ws;
    size_t off_b = 0;
    auto alloc = [&](size_t bytes) {
        size_t o = off_b;
        off_b = (off_b + bytes + 255) & ~(size_t)255;
        return o;
    };
    // zeroed region first (single memset)
    int* icnt = (int*)(ws + alloc((size_t)N * 4));
    size_t zero_bytes = off_b;
    // fully-overwritten region
    float*  xs      = (float*)(ws + alloc((size_t)N * HC * 4));
    float*  out_acc = (float*)(ws + alloc((size_t)N * HC * 4));
    float*  a_srcb  = (float*)(ws + alloc((size_t)N * HH * 4));
    float*  a_dstb  = (float*)(ws + alloc((size_t)N * HH * 4));
    int*    offb    = (int*)(ws + alloc((size_t)(N + 1) * 4));
    int*    cursor  = (int*)(ws + alloc((size_t)N * 4));
    float4* payload = (float4*)(ws + alloc((size_t)E * 16));
    float4* paylae  = (float4*)(ws + alloc((size_t)E * 16));
    unsigned short* linwt = (unsigned short*)(ws + alloc((size_t)HC * DIN * 2));
    unsigned short* w1t   = (unsigned short*)(ws + alloc((size_t)DIN * HC * 2));
    unsigned short* w2t   = (unsigned short*)(ws + alloc((size_t)CC * CC * 2));
    float* b1p = (float*)(ws + alloc((size_t)CC * 4));
    float* we  = (float*)(ws + alloc((size_t)ED * HH * 4));
    (void)ws_size; (void)n_in; (void)out_size;

    hipMemsetAsync(d_ws, 0, zero_bytes, stream);

    k_prep<<<120, 256, 0, stream>>>(lin_w, w1, w2, b1, gat_bias, lin_edge_w, att_edge,
                                    linwt, w1t, w2t, b1p, we);
    k_cnt<<<(E + 255) / 256, 256, 0, stream>>>(ei, icnt, E);
    k_xs<<<(N + 63) / 64, 256, 0, stream>>>(x, linwt, att_src, att_dst, xs, a_srcb, a_dstb, N);
    k_scan<<<1, 1024, 0, stream>>>(icnt, offb, cursor, N);
    k_fill<<<(E + 255) / 256, 256, 0, stream>>>(edge_attr, ei, a_srcb, we, cursor,
                                                payload, paylae, E);
    k_gat<<<(N + 3) / 4, 256, 0, stream>>>(xs, a_srcb, a_dstb, offb, payload, paylae,
                                           out_acc, N);
    k_mlp<<<(N + 63) / 64, 256, 0, stream>>>(out_acc, w1t, w2t, b1p, x,
                                             ln1_g, ln1_b, b2, ln2_g, ln2_b, out, N);
}

// Round 4
// 247.009 us; speedup vs baseline: 6.7394x; 1.4611x over previous
//
#include <hip/hip_runtime.h>

// GraphTransformerBlock2: GATConv(H=3,C=64, edge_dim=5, self-loops w/ mean fill)
// -> linear1 -> LN(x + .) -> linear2 -> LN(lin + .)
// All float32 I/O. edge_index int32 (2,E): src=ei[0:E], dst=ei[E:2E].
//
// R3: (a) multi-block scan (was 110us single-block);
//     (b) k_gat single-pass: no max-subtraction (logits are O(5) -> exp safe in f32,
//         softmax ratio identical), ae-sum folded into the same loop;
//     (c) xs + out_acc stored bf16 (gather bytes halved; GEMM1 rounded anyway);
//     (d) per-edge ae packed as 3x bf16 in uint2.

#define HH 3
#define CC 64
#define DIN 64
#define ED 5
#define HC 192
#define NEG_SLOPE 0.2f
#define LN_EPS 1e-5f

typedef __attribute__((ext_vector_type(8))) short bf16x8;
typedef __attribute__((ext_vector_type(4))) float f32x4;

__device__ __forceinline__ float leaky(float l) { return (l >= 0.f) ? l : NEG_SLOPE * l; }

__device__ __forceinline__ unsigned short f2bf(float f) {
    unsigned u = __float_as_uint(f);
    unsigned r = (u + 0x7FFFu + ((u >> 16) & 1u)) >> 16;   // RNE
    return (unsigned short)r;
}
__device__ __forceinline__ float bf2f(unsigned short u) {
    return __uint_as_float((unsigned)u << 16);
}

__device__ __forceinline__ bf16x8 pack8(float4 a, float4 b) {
    bf16x8 r;
    r[0] = (short)f2bf(a.x); r[1] = (short)f2bf(a.y);
    r[2] = (short)f2bf(a.z); r[3] = (short)f2bf(a.w);
    r[4] = (short)f2bf(b.x); r[5] = (short)f2bf(b.y);
    r[6] = (short)f2bf(b.z); r[7] = (short)f2bf(b.w);
    return r;
}

// ---------- prep: bf16 transposed weights + folded bias + we ----------
#define PREP_TOT (HC*DIN + DIN*HC + CC*CC + CC + ED*HH)
__global__ __launch_bounds__(256) void k_prep(const float* __restrict__ lin_w,
                                              const float* __restrict__ w1,
                                              const float* __restrict__ w2,
                                              const float* __restrict__ b1,
                                              const float* __restrict__ gat_bias,
                                              const float* __restrict__ lin_edge_w,
                                              const float* __restrict__ att_edge,
                                              unsigned short* __restrict__ linwt,
                                              unsigned short* __restrict__ w1t,
                                              unsigned short* __restrict__ w2t,
                                              float* __restrict__ b1p,
                                              float* __restrict__ we) {
    for (int i = blockIdx.x * 256 + threadIdx.x; i < PREP_TOT; i += gridDim.x * 256) {
        if (i < HC * DIN) {
            int c = i >> 6, k = i & 63;
            linwt[i] = f2bf(lin_w[k * HC + c]);
        } else if (i < 2 * HC * DIN) {
            int j = i - HC * DIN;
            int c = j / HC, k = j - c * HC;
            w1t[j] = f2bf(w1[k * CC + c]);
        } else if (i < 2 * HC * DIN + CC * CC) {
            int j = i - 2 * HC * DIN;
            int c = j >> 6, k = j & 63;
            w2t[j] = f2bf(w2[k * CC + c]);
        } else if (i < 2 * HC * DIN + CC * CC + CC) {
            int c = i - (2 * HC * DIN + CC * CC);
            float s = b1[c];
            for (int k = 0; k < HC; ++k) s += gat_bias[k] * w1[k * CC + c];
            b1p[c] = s;
        } else {
            int q = i - (2 * HC * DIN + CC * CC + CC);
            int d = q / HH, h = q - d * HH;
            float s = 0.f;
            for (int c = 0; c < CC; ++c)
                s += lin_edge_w[d * HC + h * CC + c] * att_edge[h * CC + c];
            we[q] = s;
        }
    }
}

// ---------- in-degree count ----------
__global__ __launch_bounds__(256) void k_cnt(const int* __restrict__ ei,
                                             int* __restrict__ icnt, int E) {
    int e = blockIdx.x * blockDim.x + threadIdx.x;
    if (e >= E) return;
    atomicAdd(&icnt[ei[E + e]], 1);
}

// ---------- xs = x @ lin_w (MFMA, bf16 out) + a_src/a_dst ----------
__global__ __launch_bounds__(256) void k_xs(const float* __restrict__ x,
                                            const unsigned short* __restrict__ linwt,
                                            const float* __restrict__ att_src,
                                            const float* __restrict__ att_dst,
                                            unsigned short* __restrict__ xsb,
                                            float* __restrict__ a_src,
                                            float* __restrict__ a_dst, int N) {
    int lane = threadIdx.x & 63, w = threadIdx.x >> 6;
    int l15 = lane & 15, kg = (lane >> 4) * 8;
    int nb = blockIdx.x * 64;
    int arow = nb + w * 16 + l15;
    int arow_c = min(arow, N - 1);

    f32x4 acc[12];
    #pragma unroll
    for (int ct = 0; ct < 12; ++ct) acc[ct] = (f32x4){0.f, 0.f, 0.f, 0.f};

    #pragma unroll
    for (int k0 = 0; k0 < DIN; k0 += 32) {
        const float* ap = x + (size_t)arow_c * DIN + k0 + kg;
        float4 a0 = *(const float4*)ap;
        float4 a1 = *(const float4*)(ap + 4);
        bf16x8 af = pack8(a0, a1);
        #pragma unroll
        for (int ct = 0; ct < 12; ++ct) {
            bf16x8 bf = *(const bf16x8*)(linwt + (size_t)(ct * 16 + l15) * DIN + k0 + kg);
            acc[ct] = __builtin_amdgcn_mfma_f32_16x16x32_bf16(af, bf, acc[ct], 0, 0, 0);
        }
    }

    float asv[12], adv[12];
    #pragma unroll
    for (int ct = 0; ct < 12; ++ct) {
        int c = ct * 16 + l15;
        asv[ct] = att_src[c]; adv[ct] = att_dst[c];
    }

    int rbase = nb + w * 16 + (lane >> 4) * 4;
    #pragma unroll
    for (int j = 0; j < 4; ++j) {
        int r = rbase + j;
        bool ok = r < N;
        float ps0 = 0.f, ps1 = 0.f, ps2 = 0.f, pd0 = 0.f, pd1 = 0.f, pd2 = 0.f;
        #pragma unroll
        for (int ct = 0; ct < 12; ++ct) {
            float v = acc[ct][j];
            if (ok) xsb[(size_t)r * HC + ct * 16 + l15] = f2bf(v);
            float s = v * asv[ct], d = v * adv[ct];
            if (ct < 4)      { ps0 += s; pd0 += d; }
            else if (ct < 8) { ps1 += s; pd1 += d; }
            else             { ps2 += s; pd2 += d; }
        }
        #pragma unroll
        for (int o = 1; o < 16; o <<= 1) {
            ps0 += __shfl_xor(ps0, o, 64); pd0 += __shfl_xor(pd0, o, 64);
            ps1 += __shfl_xor(ps1, o, 64); pd1 += __shfl_xor(pd1, o, 64);
            ps2 += __shfl_xor(ps2, o, 64); pd2 += __shfl_xor(pd2, o, 64);
        }
        if (ok && l15 == 0) {
            a_src[r * HH + 0] = ps0; a_src[r * HH + 1] = ps1; a_src[r * HH + 2] = ps2;
            a_dst[r * HH + 0] = pd0; a_dst[r * HH + 1] = pd1; a_dst[r * HH + 2] = pd2;
        }
    }
}

// ---------- multi-block exclusive scan (3 kernels) ----------
__global__ __launch_bounds__(256) void k_scan1(const int* __restrict__ icnt,
                                               int* __restrict__ bsum, int N) {
    int i = blockIdx.x * 256 + threadIdx.x;
    int lane = threadIdx.x & 63, wid = threadIdx.x >> 6;
    int v = (i < N) ? icnt[i] : 0;
    #pragma unroll
    for (int o = 32; o; o >>= 1) v += __shfl_xor(v, o, 64);
    __shared__ int wt[4];
    if (lane == 0) wt[wid] = v;
    __syncthreads();
    if (threadIdx.x == 0) bsum[blockIdx.x] = wt[0] + wt[1] + wt[2] + wt[3];
}

__global__ __launch_bounds__(1024) void k_scan2(const int* __restrict__ bsum,
                                                int* __restrict__ boff, int nb) {
    __shared__ int s[1024];
    int t = threadIdx.x;
    int v = (t < nb) ? bsum[t] : 0;
    s[t] = v;
    __syncthreads();
    for (int d = 1; d < 1024; d <<= 1) {
        int u = (t >= d) ? s[t - d] : 0;
        __syncthreads();
        s[t] += u;
        __syncthreads();
    }
    if (t < nb) boff[t] = s[t] - v;   // exclusive
}

__global__ __launch_bounds__(256) void k_scan3(const int* __restrict__ icnt,
                                               const int* __restrict__ boff,
                                               int* __restrict__ off,
                                               int* __restrict__ cursor, int N) {
    int i = blockIdx.x * 256 + threadIdx.x;
    int lane = threadIdx.x & 63, wid = threadIdx.x >> 6;
    int v = (i < N) ? icnt[i] : 0;
    int incl = v;
    #pragma unroll
    for (int o = 1; o < 64; o <<= 1) {
        int u = __shfl_up(incl, o, 64);
        if (lane >= o) incl += u;
    }
    __shared__ int wt[4];
    if (lane == 63) wt[wid] = incl;
    __syncthreads();
    int wpre = 0;
    for (int w = 0; w < wid; ++w) wpre += wt[w];
    int excl = boff[blockIdx.x] + wpre + incl - v;
    if (i < N) {
        off[i] = excl;
        cursor[i] = excl;
        if (i == N - 1) off[N] = excl + v;
    }
}

// ---------- payload fill (CSR order) ----------
// payload = {lp0,lp1,lp2,src}, aepk = {bf(ae0)|bf(ae1)<<16, bf(ae2)}
__global__ __launch_bounds__(256) void k_fill(const float* __restrict__ ea,
                                              const int* __restrict__ ei,
                                              const float* __restrict__ a_src,
                                              const float* __restrict__ we,
                                              int* __restrict__ cursor,
                                              float4* __restrict__ payload,
                                              uint2* __restrict__ aepk, int E) {
    int e = blockIdx.x * blockDim.x + threadIdx.x;
    if (e >= E) return;
    int s = ei[e], d = ei[E + e];
    float attr[ED];
    #pragma unroll
    for (int j = 0; j < ED; ++j) attr[j] = ea[(size_t)e * ED + j];
    float aeh[HH];
    #pragma unroll
    for (int h = 0; h < HH; ++h) {
        float a = 0.f;
        #pragma unroll
        for (int j = 0; j < ED; ++j) a += attr[j] * we[j * HH + h];
        aeh[h] = a;
    }
    int pos = atomicAdd(&cursor[d], 1);
    payload[pos] = make_float4(a_src[s * HH + 0] + aeh[0],
                               a_src[s * HH + 1] + aeh[1],
                               a_src[s * HH + 2] + aeh[2], __int_as_float(s));
    aepk[pos] = make_uint2((unsigned)f2bf(aeh[0]) | ((unsigned)f2bf(aeh[1]) << 16),
                           (unsigned)f2bf(aeh[2]));
}

// ---------- per-dst softmax + gather, SINGLE PASS (no max: logits O(5)) ----------
__global__ __launch_bounds__(256) void k_gat(const unsigned short* __restrict__ xsb,
                                             const float* __restrict__ a_src,
                                             const float* __restrict__ a_dst,
                                             const int* __restrict__ off,
                                             const float4* __restrict__ payload,
                                             const uint2* __restrict__ aepk,
                                             unsigned short* __restrict__ oaccb, int N) {
    int lane = threadIdx.x & 63;
    int wid  = threadIdx.x >> 6;
    for (int n = blockIdx.x * 4 + wid; n < N; n += gridDim.x * 4) {
        int beg = off[n], end = off[n + 1];
        int deg = end - beg;
        float ad0 = a_dst[n * HH + 0], ad1 = a_dst[n * HH + 1], ad2 = a_dst[n * HH + 2];
        float den0 = 0.f, den1 = 0.f, den2 = 0.f;
        float acc0 = 0.f, acc1 = 0.f, acc2 = 0.f;
        float s0 = 0.f, s1 = 0.f, s2 = 0.f;
        if (deg > 0) {
            float4 p = payload[beg];
            uint2  q = aepk[beg];
            for (int i = 0; i < deg; ++i) {
                float4 pn; uint2 qn;
                if (i + 1 < deg) { pn = payload[beg + i + 1]; qn = aepk[beg + i + 1]; }
                float w0 = __expf(leaky(p.x + ad0));
                float w1 = __expf(leaky(p.y + ad1));
                float w2 = __expf(leaky(p.z + ad2));
                int src = __float_as_int(p.w);
                size_t sb = (size_t)src * HC;
                float x0 = bf2f(xsb[sb + 0 * CC + lane]);
                float x1 = bf2f(xsb[sb + 1 * CC + lane]);
                float x2 = bf2f(xsb[sb + 2 * CC + lane]);
                den0 += w0; den1 += w1; den2 += w2;
                acc0 += w0 * x0; acc1 += w1 * x1; acc2 += w2 * x2;
                s0 += bf2f((unsigned short)(q.x & 0xFFFFu));
                s1 += bf2f((unsigned short)(q.x >> 16));
                s2 += bf2f((unsigned short)(q.y & 0xFFFFu));
                p = pn; q = qn;
            }
        }
        // self loop (edge attr = mean of incoming = s/deg, 0 if deg==0)
        float dc = fmaxf((float)deg, 1.0f);
        float sl0 = leaky(a_src[n * HH + 0] + ad0 + s0 / dc);
        float sl1 = leaky(a_src[n * HH + 1] + ad1 + s1 / dc);
        float sl2 = leaky(a_src[n * HH + 2] + ad2 + s2 / dc);
        float e0 = __expf(sl0), e1 = __expf(sl1), e2 = __expf(sl2);
        size_t nbse = (size_t)n * HC;
        float xn0 = bf2f(xsb[nbse + 0 * CC + lane]);
        float xn1 = bf2f(xsb[nbse + 1 * CC + lane]);
        float xn2 = bf2f(xsb[nbse + 2 * CC + lane]);
        den0 += e0; den1 += e1; den2 += e2;
        acc0 += e0 * xn0; acc1 += e1 * xn1; acc2 += e2 * xn2;
        oaccb[nbse + 0 * CC + lane] = f2bf(acc0 / den0);
        oaccb[nbse + 1 * CC + lane] = f2bf(acc1 / den1);
        oaccb[nbse + 2 * CC + lane] = f2bf(acc2 / den2);
    }
}

// ---------- fused MLP: GEMM1 -> LN1 -> GEMM2 -> LN2 (MFMA, in-reg LN) ----------
__global__ __launch_bounds__(256) void k_mlp(const unsigned short* __restrict__ oaccb,
                                             const unsigned short* __restrict__ w1t,
                                             const unsigned short* __restrict__ w2t,
                                             const float* __restrict__ b1p,
                                             const float* __restrict__ x,
                                             const float* __restrict__ g1,
                                             const float* __restrict__ be1,
                                             const float* __restrict__ b2,
                                             const float* __restrict__ g2,
                                             const float* __restrict__ be2,
                                             float* __restrict__ out, int N) {
    __shared__ unsigned short H1[64 * 72];   // [node-in-tile][feature] bf16, pad 72
    int lane = threadIdx.x & 63, w = threadIdx.x >> 6;
    int l15 = lane & 15, kg = (lane >> 4) * 8;
    int nb = blockIdx.x * 64;
    int arow = nb + w * 16 + l15;
    int arow_c = min(arow, N - 1);

    float c_b1[4], c_g1[4], c_be1[4], c_b2[4], c_g2[4], c_be2[4];
    #pragma unroll
    for (int ct = 0; ct < 4; ++ct) {
        int c = ct * 16 + l15;
        c_b1[ct] = b1p[c]; c_g1[ct] = g1[c]; c_be1[ct] = be1[c];
        c_b2[ct] = b2[c];  c_g2[ct] = g2[c]; c_be2[ct] = be2[c];
    }

    // GEMM1: [64 x 192] @ [192 x 64], A read directly as bf16
    f32x4 acc[4];
    #pragma unroll
    for (int ct = 0; ct < 4; ++ct) acc[ct] = (f32x4){0.f, 0.f, 0.f, 0.f};
    #pragma unroll
    for (int k0 = 0; k0 < HC; k0 += 32) {
        bf16x8 af = *(const bf16x8*)(oaccb + (size_t)arow_c * HC + k0 + kg);
        #pragma unroll
        for (int ct = 0; ct < 4; ++ct) {
            bf16x8 bf = *(const bf16x8*)(w1t + (size_t)(ct * 16 + l15) * HC + k0 + kg);
            acc[ct] = __builtin_amdgcn_mfma_f32_16x16x32_bf16(af, bf, acc[ct], 0, 0, 0);
        }
    }

    // epilogue1: y = acc + b1' + x ; LN1 -> h1 (regs + LDS bf16)
    int rbase = nb + w * 16 + (lane >> 4) * 4;
    int rloc0 = w * 16 + (lane >> 4) * 4;
    float h1v[4][4];
    float y[4][4];
    #pragma unroll
    for (int j = 0; j < 4; ++j) {
        int r = min(rbase + j, N - 1);
        #pragma unroll
        for (int ct = 0; ct < 4; ++ct)
            y[ct][j] = acc[ct][j] + c_b1[ct] + x[(size_t)r * DIN + ct * 16 + l15];
    }
    #pragma unroll
    for (int j = 0; j < 4; ++j) {
        float s = y[0][j] + y[1][j] + y[2][j] + y[3][j];
        #pragma unroll
        for (int o = 1; o < 16; o <<= 1) s += __shfl_xor(s, o, 64);
        float m = s * (1.0f / CC);
        float vs = 0.f;
        #pragma unroll
        for (int ct = 0; ct < 4; ++ct) { float d = y[ct][j] - m; vs += d * d; }
        #pragma unroll
        for (int o = 1; o < 16; o <<= 1) vs += __shfl_xor(vs, o, 64);
        float inv = rsqrtf(vs * (1.0f / CC) + LN_EPS);
        #pragma unroll
        for (int ct = 0; ct < 4; ++ct) {
            float h = (y[ct][j] - m) * inv * c_g1[ct] + c_be1[ct];
            h1v[ct][j] = h;
            H1[(rloc0 + j) * 72 + ct * 16 + l15] = f2bf(h);
        }
    }
    __syncthreads();

    // GEMM2: [64 x 64] @ [64 x 64]
    f32x4 acc2[4];
    #pragma unroll
    for (int ct = 0; ct < 4; ++ct) acc2[ct] = (f32x4){0.f, 0.f, 0.f, 0.f};
    #pragma unroll
    for (int k0 = 0; k0 < CC; k0 += 32) {
        bf16x8 af = *(const bf16x8*)&H1[(w * 16 + l15) * 72 + k0 + kg];
        #pragma unroll
        for (int ct = 0; ct < 4; ++ct) {
            bf16x8 bf = *(const bf16x8*)(w2t + (size_t)(ct * 16 + l15) * CC + k0 + kg);
            acc2[ct] = __builtin_amdgcn_mfma_f32_16x16x32_bf16(af, bf, acc2[ct], 0, 0, 0);
        }
    }

    // epilogue2: z = acc2 + b2 + h1 ; LN2 -> out
    #pragma unroll
    for (int j = 0; j < 4; ++j) {
        float z0 = acc2[0][j] + c_b2[0] + h1v[0][j];
        float z1 = acc2[1][j] + c_b2[1] + h1v[1][j];
        float z2 = acc2[2][j] + c_b2[2] + h1v[2][j];
        float z3 = acc2[3][j] + c_b2[3] + h1v[3][j];
        float s = z0 + z1 + z2 + z3;
        #pragma unroll
        for (int o = 1; o < 16; o <<= 1) s += __shfl_xor(s, o, 64);
        float m = s * (1.0f / CC);
        float d0 = z0 - m, d1 = z1 - m, d2 = z2 - m, d3 = z3 - m;
        float vs = d0 * d0 + d1 * d1 + d2 * d2 + d3 * d3;
        #pragma unroll
        for (int o = 1; o < 16; o <<= 1) vs += __shfl_xor(vs, o, 64);
        float inv = rsqrtf(vs * (1.0f / CC) + LN_EPS);
        int r = rbase + j;
        if (r < N) {
            out[(size_t)r * CC + 0 * 16 + l15] = d0 * inv * c_g2[0] + c_be2[0];
            out[(size_t)r * CC + 1 * 16 + l15] = d1 * inv * c_g2[1] + c_be2[1];
            out[(size_t)r * CC + 2 * 16 + l15] = d2 * inv * c_g2[2] + c_be2[2];
            out[(size_t)r * CC + 3 * 16 + l15] = d3 * inv * c_g2[3] + c_be2[3];
        }
    }
}

extern "C" void kernel_launch(void* const* d_in, const int* in_sizes, int n_in,
                              void* d_out, int out_size, void* d_ws, size_t ws_size,
                              hipStream_t stream) {
    const float* x          = (const float*)d_in[0];
    const float* edge_attr  = (const float*)d_in[1];
    const float* lin_w      = (const float*)d_in[2];
    const float* att_src    = (const float*)d_in[3];
    const float* att_dst    = (const float*)d_in[4];
    const float* lin_edge_w = (const float*)d_in[5];
    const float* att_edge   = (const float*)d_in[6];
    const float* gat_bias   = (const float*)d_in[7];
    const float* w1         = (const float*)d_in[8];
    const float* b1         = (const float*)d_in[9];
    const float* ln1_g      = (const float*)d_in[10];
    const float* ln1_b      = (const float*)d_in[11];
    const float* w2         = (const float*)d_in[12];
    const float* b2         = (const float*)d_in[13];
    const float* ln2_g      = (const float*)d_in[14];
    const float* ln2_b      = (const float*)d_in[15];
    const int*   ei         = (const int*)d_in[16];
    float* out = (float*)d_out;

    const int N = in_sizes[0] / DIN;
    const int E = in_sizes[1] / ED;
    const int nb_scan = (N + 255) / 256;

    char* ws = (char*)d_ws;
    size_t off_b = 0;
    auto alloc = [&](size_t bytes) {
        size_t o = off_b;
        off_b = (off_b + bytes + 255) & ~(size_t)255;
        return o;
    };
    // zeroed region first (single memset)
    int* icnt = (int*)(ws + alloc((size_t)N * 4));
    size_t zero_bytes = off_b;
    // fully-overwritten region
    unsigned short* xsb   = (unsigned short*)(ws + alloc((size_t)N * HC * 2));
    unsigned short* oaccb = (unsigned short*)(ws + alloc((size_t)N * HC * 2));
    float*  a_srcb  = (float*)(ws + alloc((size_t)N * HH * 4));
    float*  a_dstb  = (float*)(ws + alloc((size_t)N * HH * 4));
    int*    offb    = (int*)(ws + alloc((size_t)(N + 1) * 4));
    int*    cursor  = (int*)(ws + alloc((size_t)N * 4));
    int*    bsum    = (int*)(ws + alloc((size_t)nb_scan * 4));
    int*    boff    = (int*)(ws + alloc((size_t)nb_scan * 4));
    float4* payload = (float4*)(ws + alloc((size_t)E * 16));
    uint2*  aepk    = (uint2*)(ws + alloc((size_t)E * 8));
    unsigned short* linwt = (unsigned short*)(ws + alloc((size_t)HC * DIN * 2));
    unsigned short* w1t   = (unsigned short*)(ws + alloc((size_t)DIN * HC * 2));
    unsigned short* w2t   = (unsigned short*)(ws + alloc((size_t)CC * CC * 2));
    float* b1p = (float*)(ws + alloc((size_t)CC * 4));
    float* we  = (float*)(ws + alloc((size_t)ED * HH * 4));
    (void)ws_size; (void)n_in; (void)out_size;

    hipMemsetAsync(d_ws, 0, zero_bytes, stream);

    k_prep<<<120, 256, 0, stream>>>(lin_w, w1, w2, b1, gat_bias, lin_edge_w, att_edge,
                                    linwt, w1t, w2t, b1p, we);
    k_cnt<<<(E + 255) / 256, 256, 0, stream>>>(ei, icnt, E);
    k_xs<<<(N + 63) / 64, 256, 0, stream>>>(x, linwt, att_src, att_dst, xsb, a_srcb, a_dstb, N);
    k_scan1<<<nb_scan, 256, 0, stream>>>(icnt, bsum, N);
    k_scan2<<<1, 1024, 0, stream>>>(bsum, boff, nb_scan);
    k_scan3<<<nb_scan, 256, 0, stream>>>(icnt, boff, offb, cursor, N);
    k_fill<<<(E + 255) / 256, 256, 0, stream>>>(edge_attr, ei, a_srcb, we, cursor,
                                                payload, aepk, E);
    k_gat<<<(N + 3) / 4, 256, 0, stream>>>(xsb, a_srcb, a_dstb, offb, payload, aepk,
                                           oaccb, N);
    k_mlp<<<(N + 63) / 64, 256, 0, stream>>>(oaccb, w1t, w2t, b1p, x,
                                             ln1_g, ln1_b, b2, ln2_g, ln2_b, out, N);
}

// Round 5
// 196.757 us; speedup vs baseline: 8.4607x; 1.2554x over previous
//
#include <hip/hip_runtime.h>

// GraphTransformerBlock2: GATConv(H=3,C=64, edge_dim=5, self-loops w/ mean fill)
// -> linear1 -> LN(x + .) -> linear2 -> LN(lin + .)
// All float32 I/O. edge_index int32 (2,E): src=ei[0:E], dst=ei[E:2E].
//
// R4: k_gat two-phase: phase A edge-parallel (lane=edge) computes exp-weights
//     once (not replicated 64x / serialized 16x), phase B feature-parallel
//     gather+fma with LDS-broadcast weights, unrolled x2 (addresses known ->
//     latency hidden). Payload packed to 16B/edge (bf16 logit partials).
//     k_cnt fused into k_prep.

#define HH 3
#define CC 64
#define DIN 64
#define ED 5
#define HC 192
#define NEG_SLOPE 0.2f
#define LN_EPS 1e-5f

typedef __attribute__((ext_vector_type(8))) short bf16x8;
typedef __attribute__((ext_vector_type(4))) float f32x4;

__device__ __forceinline__ float leaky(float l) { return (l >= 0.f) ? l : NEG_SLOPE * l; }

__device__ __forceinline__ unsigned short f2bf(float f) {
    unsigned u = __float_as_uint(f);
    unsigned r = (u + 0x7FFFu + ((u >> 16) & 1u)) >> 16;   // RNE
    return (unsigned short)r;
}
__device__ __forceinline__ float bf2f(unsigned short u) {
    return __uint_as_float((unsigned)u << 16);
}

__device__ __forceinline__ bf16x8 pack8(float4 a, float4 b) {
    bf16x8 r;
    r[0] = (short)f2bf(a.x); r[1] = (short)f2bf(a.y);
    r[2] = (short)f2bf(a.z); r[3] = (short)f2bf(a.w);
    r[4] = (short)f2bf(b.x); r[5] = (short)f2bf(b.y);
    r[6] = (short)f2bf(b.z); r[7] = (short)f2bf(b.w);
    return r;
}

// ---------- prep (bf16 transposed weights + folded bias + we) FUSED with cnt ----------
#define PREP_TOT (HC*DIN + DIN*HC + CC*CC + CC + ED*HH)
#define PREP_BLOCKS 30
__global__ __launch_bounds__(256) void k_prep_cnt(const float* __restrict__ lin_w,
                                                  const float* __restrict__ w1,
                                                  const float* __restrict__ w2,
                                                  const float* __restrict__ b1,
                                                  const float* __restrict__ gat_bias,
                                                  const float* __restrict__ lin_edge_w,
                                                  const float* __restrict__ att_edge,
                                                  unsigned short* __restrict__ linwt,
                                                  unsigned short* __restrict__ w1t,
                                                  unsigned short* __restrict__ w2t,
                                                  float* __restrict__ b1p,
                                                  float* __restrict__ we,
                                                  const int* __restrict__ ei,
                                                  int* __restrict__ icnt, int E) {
    if (blockIdx.x < PREP_BLOCKS) {
        for (int i = blockIdx.x * 256 + threadIdx.x; i < PREP_TOT; i += PREP_BLOCKS * 256) {
            if (i < HC * DIN) {
                int c = i >> 6, k = i & 63;
                linwt[i] = f2bf(lin_w[k * HC + c]);
            } else if (i < 2 * HC * DIN) {
                int j = i - HC * DIN;
                int c = j / HC, k = j - c * HC;
                w1t[j] = f2bf(w1[k * CC + c]);
            } else if (i < 2 * HC * DIN + CC * CC) {
                int j = i - 2 * HC * DIN;
                int c = j >> 6, k = j & 63;
                w2t[j] = f2bf(w2[k * CC + c]);
            } else if (i < 2 * HC * DIN + CC * CC + CC) {
                int c = i - (2 * HC * DIN + CC * CC);
                float s = b1[c];
                for (int k = 0; k < HC; ++k) s += gat_bias[k] * w1[k * CC + c];
                b1p[c] = s;
            } else {
                int q = i - (2 * HC * DIN + CC * CC + CC);
                int d = q / HH, h = q - d * HH;
                float s = 0.f;
                for (int c = 0; c < CC; ++c)
                    s += lin_edge_w[d * HC + h * CC + c] * att_edge[h * CC + c];
                we[q] = s;
            }
        }
    } else {
        int nb = gridDim.x - PREP_BLOCKS;
        for (int e = (blockIdx.x - PREP_BLOCKS) * 256 + threadIdx.x; e < E; e += nb * 256)
            atomicAdd(&icnt[ei[E + e]], 1);
    }
}

// ---------- xs = x @ lin_w (MFMA, bf16 out) + a_src/a_dst ----------
__global__ __launch_bounds__(256) void k_xs(const float* __restrict__ x,
                                            const unsigned short* __restrict__ linwt,
                                            const float* __restrict__ att_src,
                                            const float* __restrict__ att_dst,
                                            unsigned short* __restrict__ xsb,
                                            float* __restrict__ a_src,
                                            float* __restrict__ a_dst, int N) {
    int lane = threadIdx.x & 63, w = threadIdx.x >> 6;
    int l15 = lane & 15, kg = (lane >> 4) * 8;
    int nb = blockIdx.x * 64;
    int arow = nb + w * 16 + l15;
    int arow_c = min(arow, N - 1);

    f32x4 acc[12];
    #pragma unroll
    for (int ct = 0; ct < 12; ++ct) acc[ct] = (f32x4){0.f, 0.f, 0.f, 0.f};

    #pragma unroll
    for (int k0 = 0; k0 < DIN; k0 += 32) {
        const float* ap = x + (size_t)arow_c * DIN + k0 + kg;
        float4 a0 = *(const float4*)ap;
        float4 a1 = *(const float4*)(ap + 4);
        bf16x8 af = pack8(a0, a1);
        #pragma unroll
        for (int ct = 0; ct < 12; ++ct) {
            bf16x8 bf = *(const bf16x8*)(linwt + (size_t)(ct * 16 + l15) * DIN + k0 + kg);
            acc[ct] = __builtin_amdgcn_mfma_f32_16x16x32_bf16(af, bf, acc[ct], 0, 0, 0);
        }
    }

    float asv[12], adv[12];
    #pragma unroll
    for (int ct = 0; ct < 12; ++ct) {
        int c = ct * 16 + l15;
        asv[ct] = att_src[c]; adv[ct] = att_dst[c];
    }

    int rbase = nb + w * 16 + (lane >> 4) * 4;
    #pragma unroll
    for (int j = 0; j < 4; ++j) {
        int r = rbase + j;
        bool ok = r < N;
        float ps0 = 0.f, ps1 = 0.f, ps2 = 0.f, pd0 = 0.f, pd1 = 0.f, pd2 = 0.f;
        #pragma unroll
        for (int ct = 0; ct < 12; ++ct) {
            float v = acc[ct][j];
            if (ok) xsb[(size_t)r * HC + ct * 16 + l15] = f2bf(v);
            float s = v * asv[ct], d = v * adv[ct];
            if (ct < 4)      { ps0 += s; pd0 += d; }
            else if (ct < 8) { ps1 += s; pd1 += d; }
            else             { ps2 += s; pd2 += d; }
        }
        #pragma unroll
        for (int o = 1; o < 16; o <<= 1) {
            ps0 += __shfl_xor(ps0, o, 64); pd0 += __shfl_xor(pd0, o, 64);
            ps1 += __shfl_xor(ps1, o, 64); pd1 += __shfl_xor(pd1, o, 64);
            ps2 += __shfl_xor(ps2, o, 64); pd2 += __shfl_xor(pd2, o, 64);
        }
        if (ok && l15 == 0) {
            a_src[r * HH + 0] = ps0; a_src[r * HH + 1] = ps1; a_src[r * HH + 2] = ps2;
            a_dst[r * HH + 0] = pd0; a_dst[r * HH + 1] = pd1; a_dst[r * HH + 2] = pd2;
        }
    }
}

// ---------- multi-block exclusive scan (3 kernels) ----------
__global__ __launch_bounds__(256) void k_scan1(const int* __restrict__ icnt,
                                               int* __restrict__ bsum, int N) {
    int i = blockIdx.x * 256 + threadIdx.x;
    int lane = threadIdx.x & 63, wid = threadIdx.x >> 6;
    int v = (i < N) ? icnt[i] : 0;
    #pragma unroll
    for (int o = 32; o; o >>= 1) v += __shfl_xor(v, o, 64);
    __shared__ int wt[4];
    if (lane == 0) wt[wid] = v;
    __syncthreads();
    if (threadIdx.x == 0) bsum[blockIdx.x] = wt[0] + wt[1] + wt[2] + wt[3];
}

__global__ __launch_bounds__(1024) void k_scan2(const int* __restrict__ bsum,
                                                int* __restrict__ boff, int nb) {
    __shared__ int s[1024];
    int t = threadIdx.x;
    int v = (t < nb) ? bsum[t] : 0;
    s[t] = v;
    __syncthreads();
    for (int d = 1; d < 1024; d <<= 1) {
        int u = (t >= d) ? s[t - d] : 0;
        __syncthreads();
        s[t] += u;
        __syncthreads();
    }
    if (t < nb) boff[t] = s[t] - v;   // exclusive
}

__global__ __launch_bounds__(256) void k_scan3(const int* __restrict__ icnt,
                                               const int* __restrict__ boff,
                                               int* __restrict__ off,
                                               int* __restrict__ cursor, int N) {
    int i = blockIdx.x * 256 + threadIdx.x;
    int lane = threadIdx.x & 63, wid = threadIdx.x >> 6;
    int v = (i < N) ? icnt[i] : 0;
    int incl = v;
    #pragma unroll
    for (int o = 1; o < 64; o <<= 1) {
        int u = __shfl_up(incl, o, 64);
        if (lane >= o) incl += u;
    }
    __shared__ int wt[4];
    if (lane == 63) wt[wid] = incl;
    __syncthreads();
    int wpre = 0;
    for (int w = 0; w < wid; ++w) wpre += wt[w];
    int excl = boff[blockIdx.x] + wpre + incl - v;
    if (i < N) {
        off[i] = excl;
        cursor[i] = excl;
        if (i == N - 1) off[N] = excl + v;
    }
}

// ---------- payload fill (CSR order), 16B/edge ----------
// pk = { bf(lp0)|bf(lp1)<<16, bf(lp2)|bf(ae0)<<16, bf(ae1)|bf(ae2)<<16, src }
__global__ __launch_bounds__(256) void k_fill(const float* __restrict__ ea,
                                              const int* __restrict__ ei,
                                              const float* __restrict__ a_src,
                                              const float* __restrict__ we,
                                              int* __restrict__ cursor,
                                              uint4* __restrict__ payload, int E) {
    int e = blockIdx.x * blockDim.x + threadIdx.x;
    if (e >= E) return;
    int s = ei[e], d = ei[E + e];
    float attr[ED];
    #pragma unroll
    for (int j = 0; j < ED; ++j) attr[j] = ea[(size_t)e * ED + j];
    float aeh[HH], lp[HH];
    #pragma unroll
    for (int h = 0; h < HH; ++h) {
        float a = 0.f;
        #pragma unroll
        for (int j = 0; j < ED; ++j) a += attr[j] * we[j * HH + h];
        aeh[h] = a;
        lp[h] = a_src[s * HH + h] + a;
    }
    int pos = atomicAdd(&cursor[d], 1);
    uint4 pk;
    pk.x = (unsigned)f2bf(lp[0])  | ((unsigned)f2bf(lp[1])  << 16);
    pk.y = (unsigned)f2bf(lp[2])  | ((unsigned)f2bf(aeh[0]) << 16);
    pk.z = (unsigned)f2bf(aeh[1]) | ((unsigned)f2bf(aeh[2]) << 16);
    pk.w = (unsigned)s;
    payload[pos] = pk;
}

// ---------- per-dst softmax + gather: two-phase (edge-parallel weights, then
//            feature-parallel gather with LDS-broadcast weights) ----------
__global__ __launch_bounds__(256) void k_gat(const unsigned short* __restrict__ xsb,
                                             const float* __restrict__ a_src,
                                             const float* __restrict__ a_dst,
                                             const int* __restrict__ off,
                                             const uint4* __restrict__ payload,
                                             unsigned short* __restrict__ oaccb, int N) {
    __shared__ float4 wbuf[4][64];
    int lane = threadIdx.x & 63;
    int wid  = threadIdx.x >> 6;
    for (int n = blockIdx.x * 4 + wid; n < N; n += gridDim.x * 4) {
        int beg = off[n], end = off[n + 1];
        int deg = end - beg;
        float ad0 = a_dst[n * HH + 0], ad1 = a_dst[n * HH + 1], ad2 = a_dst[n * HH + 2];
        float pden0 = 0.f, pden1 = 0.f, pden2 = 0.f;     // per-lane partials
        float pae0 = 0.f, pae1 = 0.f, pae2 = 0.f;
        float acc0 = 0.f, acc1 = 0.f, acc2 = 0.f;

        for (int c0 = 0; c0 < deg; c0 += 64) {
            int cn = min(deg - c0, 64);
            // --- phase A: lane = edge ---
            float w0 = 0.f, w1 = 0.f, w2 = 0.f;
            int src = 0;
            if (lane < cn) {
                uint4 p = payload[beg + c0 + lane];
                float lp0 = bf2f((unsigned short)(p.x & 0xFFFFu)) + ad0;
                float lp1 = bf2f((unsigned short)(p.x >> 16)) + ad1;
                float lp2 = bf2f((unsigned short)(p.y & 0xFFFFu)) + ad2;
                w0 = __expf(leaky(lp0));
                w1 = __expf(leaky(lp1));
                w2 = __expf(leaky(lp2));
                pae0 += bf2f((unsigned short)(p.y >> 16));
                pae1 += bf2f((unsigned short)(p.z & 0xFFFFu));
                pae2 += bf2f((unsigned short)(p.z >> 16));
                pden0 += w0; pden1 += w1; pden2 += w2;
                src = (int)p.w;
            }
            wbuf[wid][lane] = make_float4(w0, w1, w2, __int_as_float(src));
            // --- phase B: lane = feature, edges from LDS broadcast ---
            int i = 0;
            for (; i + 2 <= cn; i += 2) {
                float4 ta = wbuf[wid][i];
                float4 tb = wbuf[wid][i + 1];
                size_t sa = (size_t)__float_as_int(ta.w) * HC;
                size_t sb = (size_t)__float_as_int(tb.w) * HC;
                float xa0 = bf2f(xsb[sa + 0 * CC + lane]);
                float xa1 = bf2f(xsb[sa + 1 * CC + lane]);
                float xa2 = bf2f(xsb[sa + 2 * CC + lane]);
                float xb0 = bf2f(xsb[sb + 0 * CC + lane]);
                float xb1 = bf2f(xsb[sb + 1 * CC + lane]);
                float xb2 = bf2f(xsb[sb + 2 * CC + lane]);
                acc0 += ta.x * xa0; acc1 += ta.y * xa1; acc2 += ta.z * xa2;
                acc0 += tb.x * xb0; acc1 += tb.y * xb1; acc2 += tb.z * xb2;
            }
            if (i < cn) {
                float4 ta = wbuf[wid][i];
                size_t sa = (size_t)__float_as_int(ta.w) * HC;
                acc0 += ta.x * bf2f(xsb[sa + 0 * CC + lane]);
                acc1 += ta.y * bf2f(xsb[sa + 1 * CC + lane]);
                acc2 += ta.z * bf2f(xsb[sa + 2 * CC + lane]);
            }
        }

        // reduce per-lane partials (den, ae-sum)
        #pragma unroll
        for (int o = 32; o; o >>= 1) {
            pden0 += __shfl_xor(pden0, o, 64);
            pden1 += __shfl_xor(pden1, o, 64);
            pden2 += __shfl_xor(pden2, o, 64);
            pae0  += __shfl_xor(pae0, o, 64);
            pae1  += __shfl_xor(pae1, o, 64);
            pae2  += __shfl_xor(pae2, o, 64);
        }

        // self loop (edge attr = mean of incoming, 0 if deg==0)
        float dc = fmaxf((float)deg, 1.0f);
        float sl0 = leaky(a_src[n * HH + 0] + ad0 + pae0 / dc);
        float sl1 = leaky(a_src[n * HH + 1] + ad1 + pae1 / dc);
        float sl2 = leaky(a_src[n * HH + 2] + ad2 + pae2 / dc);
        float e0 = __expf(sl0), e1 = __expf(sl1), e2 = __expf(sl2);
        size_t nbse = (size_t)n * HC;
        float den0 = pden0 + e0, den1 = pden1 + e1, den2 = pden2 + e2;
        acc0 += e0 * bf2f(xsb[nbse + 0 * CC + lane]);
        acc1 += e1 * bf2f(xsb[nbse + 1 * CC + lane]);
        acc2 += e2 * bf2f(xsb[nbse + 2 * CC + lane]);
        oaccb[nbse + 0 * CC + lane] = f2bf(acc0 / den0);
        oaccb[nbse + 1 * CC + lane] = f2bf(acc1 / den1);
        oaccb[nbse + 2 * CC + lane] = f2bf(acc2 / den2);
    }
}

// ---------- fused MLP: GEMM1 -> LN1 -> GEMM2 -> LN2 (MFMA, in-reg LN) ----------
__global__ __launch_bounds__(256) void k_mlp(const unsigned short* __restrict__ oaccb,
                                             const unsigned short* __restrict__ w1t,
                                             const unsigned short* __restrict__ w2t,
                                             const float* __restrict__ b1p,
                                             const float* __restrict__ x,
                                             const float* __restrict__ g1,
                                             const float* __restrict__ be1,
                                             const float* __restrict__ b2,
                                             const float* __restrict__ g2,
                                             const float* __restrict__ be2,
                                             float* __restrict__ out, int N) {
    __shared__ unsigned short H1[64 * 72];   // [node-in-tile][feature] bf16, pad 72
    int lane = threadIdx.x & 63, w = threadIdx.x >> 6;
    int l15 = lane & 15, kg = (lane >> 4) * 8;
    int nb = blockIdx.x * 64;
    int arow = nb + w * 16 + l15;
    int arow_c = min(arow, N - 1);

    float c_b1[4], c_g1[4], c_be1[4], c_b2[4], c_g2[4], c_be2[4];
    #pragma unroll
    for (int ct = 0; ct < 4; ++ct) {
        int c = ct * 16 + l15;
        c_b1[ct] = b1p[c]; c_g1[ct] = g1[c]; c_be1[ct] = be1[c];
        c_b2[ct] = b2[c];  c_g2[ct] = g2[c]; c_be2[ct] = be2[c];
    }

    // GEMM1: [64 x 192] @ [192 x 64], A read directly as bf16
    f32x4 acc[4];
    #pragma unroll
    for (int ct = 0; ct < 4; ++ct) acc[ct] = (f32x4){0.f, 0.f, 0.f, 0.f};
    #pragma unroll
    for (int k0 = 0; k0 < HC; k0 += 32) {
        bf16x8 af = *(const bf16x8*)(oaccb + (size_t)arow_c * HC + k0 + kg);
        #pragma unroll
        for (int ct = 0; ct < 4; ++ct) {
            bf16x8 bf = *(const bf16x8*)(w1t + (size_t)(ct * 16 + l15) * HC + k0 + kg);
            acc[ct] = __builtin_amdgcn_mfma_f32_16x16x32_bf16(af, bf, acc[ct], 0, 0, 0);
        }
    }

    // epilogue1: y = acc + b1' + x ; LN1 -> h1 (regs + LDS bf16)
    int rbase = nb + w * 16 + (lane >> 4) * 4;
    int rloc0 = w * 16 + (lane >> 4) * 4;
    float h1v[4][4];
    float y[4][4];
    #pragma unroll
    for (int j = 0; j < 4; ++j) {
        int r = min(rbase + j, N - 1);
        #pragma unroll
        for (int ct = 0; ct < 4; ++ct)
            y[ct][j] = acc[ct][j] + c_b1[ct] + x[(size_t)r * DIN + ct * 16 + l15];
    }
    #pragma unroll
    for (int j = 0; j < 4; ++j) {
        float s = y[0][j] + y[1][j] + y[2][j] + y[3][j];
        #pragma unroll
        for (int o = 1; o < 16; o <<= 1) s += __shfl_xor(s, o, 64);
        float m = s * (1.0f / CC);
        float vs = 0.f;
        #pragma unroll
        for (int ct = 0; ct < 4; ++ct) { float d = y[ct][j] - m; vs += d * d; }
        #pragma unroll
        for (int o = 1; o < 16; o <<= 1) vs += __shfl_xor(vs, o, 64);
        float inv = rsqrtf(vs * (1.0f / CC) + LN_EPS);
        #pragma unroll
        for (int ct = 0; ct < 4; ++ct) {
            float h = (y[ct][j] - m) * inv * c_g1[ct] + c_be1[ct];
            h1v[ct][j] = h;
            H1[(rloc0 + j) * 72 + ct * 16 + l15] = f2bf(h);
        }
    }
    __syncthreads();

    // GEMM2: [64 x 64] @ [64 x 64]
    f32x4 acc2[4];
    #pragma unroll
    for (int ct = 0; ct < 4; ++ct) acc2[ct] = (f32x4){0.f, 0.f, 0.f, 0.f};
    #pragma unroll
    for (int k0 = 0; k0 < CC; k0 += 32) {
        bf16x8 af = *(const bf16x8*)&H1[(w * 16 + l15) * 72 + k0 + kg];
        #pragma unroll
        for (int ct = 0; ct < 4; ++ct) {
            bf16x8 bf = *(const bf16x8*)(w2t + (size_t)(ct * 16 + l15) * CC + k0 + kg);
            acc2[ct] = __builtin_amdgcn_mfma_f32_16x16x32_bf16(af, bf, acc2[ct], 0, 0, 0);
        }
    }

    // epilogue2: z = acc2 + b2 + h1 ; LN2 -> out
    #pragma unroll
    for (int j = 0; j < 4; ++j) {
        float z0 = acc2[0][j] + c_b2[0] + h1v[0][j];
        float z1 = acc2[1][j] + c_b2[1] + h1v[1][j];
        float z2 = acc2[2][j] + c_b2[2] + h1v[2][j];
        float z3 = acc2[3][j] + c_b2[3] + h1v[3][j];
        float s = z0 + z1 + z2 + z3;
        #pragma unroll
        for (int o = 1; o < 16; o <<= 1) s += __shfl_xor(s, o, 64);
        float m = s * (1.0f / CC);
        float d0 = z0 - m, d1 = z1 - m, d2 = z2 - m, d3 = z3 - m;
        float vs = d0 * d0 + d1 * d1 + d2 * d2 + d3 * d3;
        #pragma unroll
        for (int o = 1; o < 16; o <<= 1) vs += __shfl_xor(vs, o, 64);
        float inv = rsqrtf(vs * (1.0f / CC) + LN_EPS);
        int r = rbase + j;
        if (r < N) {
            out[(size_t)r * CC + 0 * 16 + l15] = d0 * inv * c_g2[0] + c_be2[0];
            out[(size_t)r * CC + 1 * 16 + l15] = d1 * inv * c_g2[1] + c_be2[1];
            out[(size_t)r * CC + 2 * 16 + l15] = d2 * inv * c_g2[2] + c_be2[2];
            out[(size_t)r * CC + 3 * 16 + l15] = d3 * inv * c_g2[3] + c_be2[3];
        }
    }
}

extern "C" void kernel_launch(void* const* d_in, const int* in_sizes, int n_in,
                              void* d_out, int out_size, void* d_ws, size_t ws_size,
                              hipStream_t stream) {
    const float* x          = (const float*)d_in[0];
    const float* edge_attr  = (const float*)d_in[1];
    const float* lin_w      = (const float*)d_in[2];
    const float* att_src    = (const float*)d_in[3];
    const float* att_dst    = (const float*)d_in[4];
    const float* lin_edge_w = (const float*)d_in[5];
    const float* att_edge   = (const float*)d_in[6];
    const float* gat_bias   = (const float*)d_in[7];
    const float* w1         = (const float*)d_in[8];
    const float* b1         = (const float*)d_in[9];
    const float* ln1_g      = (const float*)d_in[10];
    const float* ln1_b      = (const float*)d_in[11];
    const float* w2         = (const float*)d_in[12];
    const float* b2         = (const float*)d_in[13];
    const float* ln2_g      = (const float*)d_in[14];
    const float* ln2_b      = (const float*)d_in[15];
    const int*   ei         = (const int*)d_in[16];
    float* out = (float*)d_out;

    const int N = in_sizes[0] / DIN;
    const int E = in_sizes[1] / ED;
    const int nb_scan = (N + 255) / 256;

    char* ws = (char*)d_ws;
    size_t off_b = 0;
    auto alloc = [&](size_t bytes) {
        size_t o = off_b;
        off_b = (off_b + bytes + 255) & ~(size_t)255;
        return o;
    };
    // zeroed region first (single memset)
    int* icnt = (int*)(ws + alloc((size_t)N * 4));
    size_t zero_bytes = off_b;
    // fully-overwritten region
    unsigned short* xsb   = (unsigned short*)(ws + alloc((size_t)N * HC * 2));
    unsigned short* oaccb = (unsigned short*)(ws + alloc((size_t)N * HC * 2));
    float*  a_srcb  = (float*)(ws + alloc((size_t)N * HH * 4));
    float*  a_dstb  = (float*)(ws + alloc((size_t)N * HH * 4));
    int*    offb    = (int*)(ws + alloc((size_t)(N + 1) * 4));
    int*    cursor  = (int*)(ws + alloc((size_t)N * 4));
    int*    bsum    = (int*)(ws + alloc((size_t)nb_scan * 4));
    int*    boff    = (int*)(ws + alloc((size_t)nb_scan * 4));
    uint4*  payload = (uint4*)(ws + alloc((size_t)E * 16));
    unsigned short* linwt = (unsigned short*)(ws + alloc((size_t)HC * DIN * 2));
    unsigned short* w1t   = (unsigned short*)(ws + alloc((size_t)DIN * HC * 2));
    unsigned short* w2t   = (unsigned short*)(ws + alloc((size_t)CC * CC * 2));
    float* b1p = (float*)(ws + alloc((size_t)CC * 4));
    float* we  = (float*)(ws + alloc((size_t)ED * HH * 4));
    (void)ws_size; (void)n_in; (void)out_size;

    hipMemsetAsync(d_ws, 0, zero_bytes, stream);

    k_prep_cnt<<<PREP_BLOCKS + (E + 255) / 256, 256, 0, stream>>>(
        lin_w, w1, w2, b1, gat_bias, lin_edge_w, att_edge,
        linwt, w1t, w2t, b1p, we, ei, icnt, E);
    k_xs<<<(N + 63) / 64, 256, 0, stream>>>(x, linwt, att_src, att_dst, xsb, a_srcb, a_dstb, N);
    k_scan1<<<nb_scan, 256, 0, stream>>>(icnt, bsum, N);
    k_scan2<<<1, 1024, 0, stream>>>(bsum, boff, nb_scan);
    k_scan3<<<nb_scan, 256, 0, stream>>>(icnt, boff, offb, cursor, N);
    k_fill<<<(E + 255) / 256, 256, 0, stream>>>(edge_attr, ei, a_srcb, we, cursor,
                                                payload, E);
    k_gat<<<(N + 3) / 4, 256, 0, stream>>>(xsb, a_srcb, a_dstb, offb, payload, oaccb, N);
    k_mlp<<<(N + 63) / 64, 256, 0, stream>>>(oaccb, w1t, w2t, b1p, x,
                                             ln1_g, ln1_b, b2, ln2_g, ln2_b, out, N);
}